// Round 2
// baseline (961.675 us; speedup 1.0000x reference)
//
#include <hip/hip_runtime.h>
#include <hip/hip_bf16.h>

#define CCH 128
#define WSTRIDE 132   // 128 + 4 pad

typedef __hip_bfloat16 bf16;

__device__ __forceinline__ float toF(const bf16 v) { return __bfloat162float(v); }
__device__ __forceinline__ float toF(const float v) { return v; }
__device__ __forceinline__ float ldf(const void* p, int i, bool f32) {
  return f32 ? ((const float*)p)[i] : toF(((const bf16*)p)[i]);
}

// ---------------- dtype detection ----------------
// flags[0] = 1 if float buffers are fp32 (else bf16); flags[1] = 1 if edge_index is int64
__global__ void k_detect(const unsigned int* __restrict__ xw,
                         const unsigned int* __restrict__ eiw,
                         int* __restrict__ flags) {
  __shared__ int cf, cz;
  int t = threadIdx.x;
  if (t == 0) { cf = 0; cz = 0; }
  __syncthreads();
  unsigned w = xw[t];                 // word t of x
  int ex = (w >> 23) & 0xff;          // fp32 exponent field
  if (w == 0u || (ex >= 90 && ex <= 150)) atomicAdd(&cf, 1);
  if (eiw[2 * t + 1] != 0u) atomicAdd(&cz, 1);  // high words all-zero => int64
  __syncthreads();
  if (t == 0) { flags[0] = (cf >= 200) ? 1 : 0; flags[1] = (cz == 0) ? 1 : 0; }
}

__device__ __forceinline__ int ldidx(const void* ei, size_t i, bool i64) {
  return i64 ? (int)((const long long*)ei)[i] : ((const int*)ei)[i];
}

// ---------------- CSR build ----------------
__global__ void k_hist(const void* __restrict__ ei, int* __restrict__ deg, int E,
                       const int* __restrict__ flags) {
  bool i64 = flags[1] != 0;
  int e = blockIdx.x * 256 + threadIdx.x;
  if (e < E) atomicAdd(&deg[ldidx(ei, (size_t)E + e, i64)], 1);
}

__global__ void k_scan1(const int* __restrict__ deg, int* __restrict__ bsum, int n) {
  __shared__ int s[256];
  int t = threadIdx.x, i = blockIdx.x * 256 + t;
  s[t] = (i < n) ? deg[i] : 0;
  __syncthreads();
  for (int off = 128; off > 0; off >>= 1) {
    if (t < off) s[t] += s[t + off];
    __syncthreads();
  }
  if (t == 0) bsum[blockIdx.x] = s[0];
}

__global__ void k_scan2(const int* __restrict__ bsum, int* __restrict__ boff, int nb) {
  __shared__ int s[256];
  int t = threadIdx.x;
  int v = (t < nb) ? bsum[t] : 0;
  s[t] = v; __syncthreads();
  for (int off = 1; off < 256; off <<= 1) {
    int tv = (t >= off) ? s[t - off] : 0;
    __syncthreads();
    s[t] += tv;
    __syncthreads();
  }
  if (t < nb) boff[t] = s[t] - v;   // exclusive
}

__global__ void k_scan3(const int* __restrict__ deg, const int* __restrict__ boff,
                        int* __restrict__ rowptr, int n, int Etot) {
  __shared__ int s[256];
  int t = threadIdx.x, i = blockIdx.x * 256 + t;
  int v = (i < n) ? deg[i] : 0;
  s[t] = v; __syncthreads();
  for (int off = 1; off < 256; off <<= 1) {
    int tv = (t >= off) ? s[t - off] : 0;
    __syncthreads();
    s[t] += tv;
    __syncthreads();
  }
  if (i < n) rowptr[i] = boff[blockIdx.x] + s[t] - v;
  if (i == 0) rowptr[n] = Etot;
}

__global__ void k_scatter(const void* __restrict__ ei, const int* __restrict__ rowptr,
                          int* __restrict__ cnt, int* __restrict__ esrc, int E,
                          const int* __restrict__ flags) {
  bool i64 = flags[1] != 0;
  int e = blockIdx.x * 256 + threadIdx.x;
  if (e < E) {
    int d = ldidx(ei, (size_t)E + e, i64);
    int s = ldidx(ei, (size_t)e, i64);
    int pos = rowptr[d] + atomicAdd(&cnt[d], 1);
    esrc[pos] = s;
  }
}

// ---------------- GEMM: Y[n][c] = sum_k X[n][k]*W[c][k] (+bias) ----------------
// WMODE 0: W[c][k]=wa[c][k]-wa[c][k+128]; 1: wa[c][k+128]; 2: wb[c][k]
// BMODE 0: +bias[c]; 1: none; 2: +deg[n]*bias[c]
// EPI 0: store f32; 1: relu + row-L2-norm, store f32; 2: final store (dtype by flag)
// XMODE 0: X dtype per flag; 1: X is always float (intermediate)
// In-place (Y==X) is safe: each 32-lane group fully reads its row before storing it.
template <int WMODE, int BMODE, int EPI, int XMODE>
__global__ __launch_bounds__(256) void k_gemm(const void* __restrict__ X,
                                              const void* __restrict__ W,
                                              const void* __restrict__ bias,
                                              const int* __restrict__ rowptr,
                                              void* __restrict__ Y, int nNodes,
                                              const int* __restrict__ flags) {
  __shared__ float Wt[CCH * WSTRIDE];  // transposed: Wt[k*WSTRIDE + c]
  __shared__ float bl[CCH];
  const bool f32 = flags[0] != 0;
  const int tid = threadIdx.x;

  for (int i = tid; i < CCH * CCH; i += 256) {
    int k = i & 127, c = i >> 7;
    float v;
    if (WMODE == 0)      v = ldf(W, c * 256 + k, f32) - ldf(W, c * 256 + 128 + k, f32);
    else if (WMODE == 1) v = ldf(W, c * 256 + 128 + k, f32);
    else                 v = ldf(W, c * 128 + k, f32);
    Wt[k * WSTRIDE + c] = v;
  }
  if (tid < CCH) bl[tid] = (BMODE == 1) ? 0.f : ldf(bias, tid, f32);
  __syncthreads();

  const int c0 = (tid & 31) * 4;
  const int nsub = tid >> 5;

  for (int it = 0; it < 8; ++it) {
    int node = blockIdx.x * 64 + it * 8 + nsub;
    if (node >= nNodes) continue;

    float a0, a1, a2, a3;
    if (BMODE == 2) {
      float dn = (float)(rowptr[node + 1] - rowptr[node]);
      a0 = dn * bl[c0]; a1 = dn * bl[c0 + 1]; a2 = dn * bl[c0 + 2]; a3 = dn * bl[c0 + 3];
    } else {
      a0 = bl[c0]; a1 = bl[c0 + 1]; a2 = bl[c0 + 2]; a3 = bl[c0 + 3];
    }

    auto dot = [&](const auto* xr) {
#pragma unroll 4
      for (int k = 0; k < CCH; ++k) {
        float xk = toF(xr[k]);
        const float4 wv = *(const float4*)&Wt[k * WSTRIDE + c0];
        a0 += xk * wv.x; a1 += xk * wv.y; a2 += xk * wv.z; a3 += xk * wv.w;
      }
    };
    if (XMODE == 1 || f32) dot((const float*)X + (size_t)node * CCH);
    else                   dot((const bf16*)X + (size_t)node * CCH);

    if (EPI == 0) {
      float4 o{a0, a1, a2, a3};
      *(float4*)&((float*)Y)[(size_t)node * CCH + c0] = o;
    } else if (EPI == 1) {
      float v0 = fmaxf(a0, 0.f), v1 = fmaxf(a1, 0.f), v2 = fmaxf(a2, 0.f), v3 = fmaxf(a3, 0.f);
      float ss = v0 * v0 + v1 * v1 + v2 * v2 + v3 * v3;
#pragma unroll
      for (int m = 1; m < 32; m <<= 1) ss += __shfl_xor(ss, m, 64);
      float inv = 1.0f / fmaxf(sqrtf(ss), 1e-12f);
      float4 o{v0 * inv, v1 * inv, v2 * inv, v3 * inv};
      *(float4*)&((float*)Y)[(size_t)node * CCH + c0] = o;
    } else {
      if (f32) {
        float4 o{a0, a1, a2, a3};
        *(float4*)&((float*)Y)[(size_t)node * CCH + c0] = o;
      } else {
        bf16* yo = (bf16*)Y + (size_t)node * CCH + c0;
        yo[0] = __float2bfloat16(a0); yo[1] = __float2bfloat16(a1);
        yo[2] = __float2bfloat16(a2); yo[3] = __float2bfloat16(a3);
      }
    }
  }
}

// ---------------- edge aggregation (32-lane group per node halves? wave per node) ----------------
__global__ __launch_bounds__(256) void k_aggr(float* __restrict__ A1M,
                                              const float* __restrict__ A2,
                                              const int* __restrict__ rowptr,
                                              const int* __restrict__ esrc,
                                              const void* __restrict__ g,
                                              const void* __restrict__ be,
                                              const void* __restrict__ rm,
                                              const void* __restrict__ rv,
                                              int nNodes,
                                              const int* __restrict__ flags) {
  const bool f32 = flags[0] != 0;
  int node = blockIdx.x * 4 + (threadIdx.x >> 6);
  if (node >= nNodes) return;
  int lane = threadIdx.x & 63;
  int c = lane * 2;

  float2 a1 = *(const float2*)&A1M[(size_t)node * CCH + c];
  int r0 = rowptr[node], r1 = rowptr[node + 1];
  float s0 = 0.f, s1 = 0.f;
#pragma unroll 2
  for (int e = r0; e < r1; ++e) {
    int s = esrc[e];
    float2 v = *(const float2*)&A2[(size_t)s * CCH + c];
    s0 += fmaxf(a1.x + v.x, 0.f);
    s1 += fmaxf(a1.y + v.y, 0.f);
  }
  float dn = (float)(r1 - r0);
  float sc0 = ldf(g, c, f32)     * rsqrtf(ldf(rv, c, f32)     + 1e-5f);
  float sc1 = ldf(g, c + 1, f32) * rsqrtf(ldf(rv, c + 1, f32) + 1e-5f);
  float sh0 = ldf(be, c, f32)     - ldf(rm, c, f32)     * sc0;
  float sh1 = ldf(be, c + 1, f32) - ldf(rm, c + 1, f32) * sc1;
  float2 o{sc0 * s0 + dn * sh0, sc1 * s1 + dn * sh1};
  *(float2*)&A1M[(size_t)node * CCH + c] = o;
}

// ---------------- launch ----------------
extern "C" void kernel_launch(void* const* d_in, const int* in_sizes, int n_in,
                              void* d_out, int out_size, void* d_ws, size_t ws_size,
                              hipStream_t stream) {
  const void* x   = d_in[0];
  const void* ei  = d_in[1];
  const void* w1a = d_in[2];
  const void* b1a = d_in[3];
  const void* g1  = d_in[4];
  const void* be1 = d_in[5];
  const void* rm1 = d_in[6];
  const void* rv1 = d_in[7];
  const void* w1b = d_in[8];
  const void* b1b = d_in[9];
  const void* w2a = d_in[10];
  const void* b2a = d_in[11];
  const void* g2  = d_in[12];
  const void* be2 = d_in[13];
  const void* rm2 = d_in[14];
  const void* rv2 = d_in[15];
  const void* w2b = d_in[16];
  const void* b2b = d_in[17];

  const int N = in_sizes[0] / CCH;   // 50000
  const int E = in_sizes[1] / 2;     // 600000
  const size_t NC = (size_t)N * CCH;

  // ws layout: ints first (small, guaranteed in-bounds), then 2 fp32 node buffers
  int* flags  = (int*)d_ws;              // 4
  int* deg    = flags + 4;               // N
  int* cnt    = deg + N;                 // N
  int* rowptr = cnt + N;                 // N+1
  int* bsum   = rowptr + N + 1;          // 256
  int* boff   = bsum + 256;              // 256
  int* esrc   = boff + 256;              // E
  uintptr_t pb = ((uintptr_t)(esrc + E) + 63) & ~(uintptr_t)63;
  float* B0 = (float*)pb;                // NC floats
  float* B1 = B0 + NC;                   // NC floats
  // total ≈ 3 MB + 51.2 MB

  const int gE = (E + 255) / 256;
  const int gS = (N + 255) / 256;   // 196
  const int gG = (N + 63) / 64;     // 782
  const int gA = (N + 3) / 4;       // 12500

  k_detect<<<1, 256, 0, stream>>>((const unsigned int*)x, (const unsigned int*)ei, flags);
  hipMemsetAsync(deg, 0, sizeof(int) * 2 * (size_t)N, stream);  // deg + cnt
  k_hist<<<gE, 256, 0, stream>>>(ei, deg, E, flags);
  k_scan1<<<gS, 256, 0, stream>>>(deg, bsum, N);
  k_scan2<<<1, 256, 0, stream>>>(bsum, boff, gS);
  k_scan3<<<gS, 256, 0, stream>>>(deg, boff, rowptr, N, E);
  k_scatter<<<gE, 256, 0, stream>>>(ei, rowptr, cnt, esrc, E, flags);

  // ---- layer 1 ----
  k_gemm<0, 0, 0, 0><<<gG, 256, 0, stream>>>(x, w1a, b1a, nullptr, B0, N, flags);  // A1 -> B0
  k_gemm<1, 1, 0, 0><<<gG, 256, 0, stream>>>(x, w1a, nullptr, nullptr, B1, N, flags); // A2 -> B1
  k_aggr<<<gA, 256, 0, stream>>>(B0, B1, rowptr, esrc, g1, be1, rm1, rv1, N, flags);  // M -> B0
  k_gemm<2, 2, 1, 1><<<gG, 256, 0, stream>>>(B0, w1b, b1b, rowptr, B1, N, flags);     // H -> B1

  // ---- layer 2 ----
  k_gemm<0, 0, 0, 1><<<gG, 256, 0, stream>>>(B1, w2a, b2a, nullptr, B0, N, flags);    // A1 -> B0
  k_gemm<1, 1, 0, 1><<<gG, 256, 0, stream>>>(B1, w2a, nullptr, nullptr, B1, N, flags); // A2 -> B1 (in-place, safe)
  k_aggr<<<gA, 256, 0, stream>>>(B0, B1, rowptr, esrc, g2, be2, rm2, rv2, N, flags);  // M -> B0
  k_gemm<2, 2, 2, 1><<<gG, 256, 0, stream>>>(B0, w2b, b2b, rowptr, d_out, N, flags);  // out
}

// Round 3
// 495.641 us; speedup vs baseline: 1.9403x; 1.9403x over previous
//
#include <hip/hip_runtime.h>

#define CCH 128

// ---------------- edge-index width detection ----------------
// flags[1] = 1 if edge_index is int64 (all odd 32-bit words zero), else int32
__global__ void k_detect(const unsigned int* __restrict__ eiw, int* __restrict__ flags) {
  __shared__ int cz;
  int t = threadIdx.x;
  if (t == 0) cz = 0;
  __syncthreads();
  if (eiw[2 * t + 1] != 0u) atomicAdd(&cz, 1);
  __syncthreads();
  if (t == 0) flags[1] = (cz == 0) ? 1 : 0;
}

__device__ __forceinline__ int ldidx(const void* ei, size_t i, bool i64) {
  return i64 ? (int)((const long long*)ei)[i] : ((const int*)ei)[i];
}

// ---------------- CSR build ----------------
__global__ void k_hist(const void* __restrict__ ei, int* __restrict__ deg, int E,
                       const int* __restrict__ flags) {
  bool i64 = flags[1] != 0;
  int e = blockIdx.x * 256 + threadIdx.x;
  if (e < E) atomicAdd(&deg[ldidx(ei, (size_t)E + e, i64)], 1);
}

__global__ void k_scan1(const int* __restrict__ deg, int* __restrict__ bsum, int n) {
  __shared__ int s[256];
  int t = threadIdx.x, i = blockIdx.x * 256 + t;
  s[t] = (i < n) ? deg[i] : 0;
  __syncthreads();
  for (int off = 128; off > 0; off >>= 1) {
    if (t < off) s[t] += s[t + off];
    __syncthreads();
  }
  if (t == 0) bsum[blockIdx.x] = s[0];
}

__global__ void k_scan2(const int* __restrict__ bsum, int* __restrict__ boff, int nb) {
  __shared__ int s[256];
  int t = threadIdx.x;
  int v = (t < nb) ? bsum[t] : 0;
  s[t] = v; __syncthreads();
  for (int off = 1; off < 256; off <<= 1) {
    int tv = (t >= off) ? s[t - off] : 0;
    __syncthreads();
    s[t] += tv;
    __syncthreads();
  }
  if (t < nb) boff[t] = s[t] - v;   // exclusive
}

__global__ void k_scan3(const int* __restrict__ deg, const int* __restrict__ boff,
                        int* __restrict__ rowptr, int n, int Etot) {
  __shared__ int s[256];
  int t = threadIdx.x, i = blockIdx.x * 256 + t;
  int v = (i < n) ? deg[i] : 0;
  s[t] = v; __syncthreads();
  for (int off = 1; off < 256; off <<= 1) {
    int tv = (t >= off) ? s[t - off] : 0;
    __syncthreads();
    s[t] += tv;
    __syncthreads();
  }
  if (i < n) rowptr[i] = boff[blockIdx.x] + s[t] - v;
  if (i == 0) rowptr[n] = Etot;
}

__global__ void k_scatter(const void* __restrict__ ei, const int* __restrict__ rowptr,
                          int* __restrict__ cnt, int* __restrict__ esrc, int E,
                          const int* __restrict__ flags) {
  bool i64 = flags[1] != 0;
  int e = blockIdx.x * 256 + threadIdx.x;
  if (e < E) {
    int d = ldidx(ei, (size_t)E + e, i64);
    int s = ldidx(ei, (size_t)e, i64);
    int pos = rowptr[d] + atomicAdd(&cnt[d], 1);
    esrc[pos] = s;
  }
}

// ---------------- tiled fp32 GEMM: Y[n][c] = sum_k X[n][k]*W'[c][k] (+bias) ----
// WMODE 0: W'[c][k]=wa[c][k]-wa[c][k+128]; 1: wa[c][k+128]; 2: wb[c][k]
// BMODE 0: +bias[c]; 1: none; 2: +deg[n]*bias[c]
// EPI   0: store;    1: relu + row-L2-normalize then store
// Tile: 64 rows x 128 cols per block; K processed in two 64-wide phases.
// LDS: wt[k][c] 32KB + xt[k][r] 16KB = 48KB -> 3 blocks/CU.
// Thread micro-tile: 4 rows x 8 cols (r0=(t&15)*4, c0=(t>>4)*8).
// In-place (Y==X) is safe: all global reads of own rows precede epilogue stores.
template <int WMODE, int BMODE, int EPI>
__global__ __launch_bounds__(256, 3) void k_gemm(const float* X, const float* W,
                                                 const float* bias,
                                                 const int* __restrict__ rowptr,
                                                 float* Y, int nN) {
  __shared__ float wt[64 * 128];  // [k_local][c]
  __shared__ float xt[64 * 64];   // [k_local][r]  (reused as norm scratch in EPI1)
  const int t = threadIdx.x;
  const int base = blockIdx.x * 64;
  const int r0 = (t & 15) * 4;
  const int c0 = (t >> 4) * 8;

  float bias_r[8];
  if (BMODE != 1) {
    *(float4*)&bias_r[0] = *(const float4*)&bias[c0];
    *(float4*)&bias_r[4] = *(const float4*)&bias[c0 + 4];
  }
  float deg_r[4];
  if (BMODE == 2) {
#pragma unroll
    for (int i = 0; i < 4; ++i) {
      int node = base + r0 + i;
      deg_r[i] = (node < nN) ? (float)(rowptr[node + 1] - rowptr[node]) : 0.f;
    }
  }

  float acc[4][8];
#pragma unroll
  for (int i = 0; i < 4; ++i)
#pragma unroll
    for (int j = 0; j < 8; ++j) acc[i][j] = 0.f;

  for (int ph = 0; ph < 2; ++ph) {
    if (ph) __syncthreads();           // previous compute must finish before restage
    const int kb = ph * 64;

    // ---- stage W half: 512 4x4 chunks, 2/thread; kc fast for coalesced global ----
    {
      int ch = t;
      for (int it = 0; it < 2; ++it, ch += 256) {
        int kc = ch & 15, cg = ch >> 4;     // cg in [0,32)
        int k4 = kb + kc * 4;
        float4 row[4];
#pragma unroll
        for (int i = 0; i < 4; ++i) {
          int c = cg * 4 + i;
          if (WMODE == 0) {
            float4 a = *(const float4*)&W[c * 256 + k4];
            float4 b = *(const float4*)&W[c * 256 + 128 + k4];
            row[i] = make_float4(a.x - b.x, a.y - b.y, a.z - b.z, a.w - b.w);
          } else if (WMODE == 1) {
            row[i] = *(const float4*)&W[c * 256 + 128 + k4];
          } else {
            row[i] = *(const float4*)&W[c * 128 + k4];
          }
        }
#pragma unroll
        for (int j = 0; j < 4; ++j) {   // register transpose -> wt[k][c] contiguous in c
          float4 v = make_float4(((const float*)&row[0])[j], ((const float*)&row[1])[j],
                                 ((const float*)&row[2])[j], ((const float*)&row[3])[j]);
          *(float4*)&wt[(kc * 4 + j) * 128 + cg * 4] = v;
        }
      }
    }
    // ---- stage X tile half: 256 chunks, 1/thread; rg=(t&15), kc=(t>>4) ----
    {
      int rg = t & 15, kc = t >> 4;
      int k4 = kb + kc * 4;
      float4 row[4];
#pragma unroll
      for (int i = 0; i < 4; ++i) {
        int node = base + rg * 4 + i;
        row[i] = (node < nN) ? *(const float4*)&X[(size_t)node * CCH + k4]
                             : make_float4(0.f, 0.f, 0.f, 0.f);
      }
#pragma unroll
      for (int j = 0; j < 4; ++j) {
        float4 v = make_float4(((const float*)&row[0])[j], ((const float*)&row[1])[j],
                               ((const float*)&row[2])[j], ((const float*)&row[3])[j]);
        *(float4*)&xt[(kc * 4 + j) * 64 + rg * 4] = v;
      }
    }
    __syncthreads();

    // ---- compute: 64 k-steps, 32 FMAs each ----
#pragma unroll 4
    for (int k = 0; k < 64; ++k) {
      float4 av = *(const float4*)&xt[k * 64 + r0];
      float4 b0 = *(const float4*)&wt[k * 128 + c0];
      float4 b1 = *(const float4*)&wt[k * 128 + c0 + 4];
      const float* ap = (const float*)&av;
      const float* bp = (const float*)&b0;
      const float* bq = (const float*)&b1;
#pragma unroll
      for (int i = 0; i < 4; ++i) {
        float a = ap[i];
        acc[i][0] = fmaf(a, bp[0], acc[i][0]);
        acc[i][1] = fmaf(a, bp[1], acc[i][1]);
        acc[i][2] = fmaf(a, bp[2], acc[i][2]);
        acc[i][3] = fmaf(a, bp[3], acc[i][3]);
        acc[i][4] = fmaf(a, bq[0], acc[i][4]);
        acc[i][5] = fmaf(a, bq[1], acc[i][5]);
        acc[i][6] = fmaf(a, bq[2], acc[i][6]);
        acc[i][7] = fmaf(a, bq[3], acc[i][7]);
      }
    }
  }

  // ---- epilogue ----
  if (EPI == 0) {
#pragma unroll
    for (int i = 0; i < 4; ++i) {
      int node = base + r0 + i;
      if (node >= nN) continue;
      float v[8];
#pragma unroll
      for (int j = 0; j < 8; ++j) {
        float b = (BMODE == 0) ? bias_r[j] : (BMODE == 2) ? deg_r[i] * bias_r[j] : 0.f;
        v[j] = acc[i][j] + b;
      }
      *(float4*)&Y[(size_t)node * CCH + c0]     = make_float4(v[0], v[1], v[2], v[3]);
      *(float4*)&Y[(size_t)node * CCH + c0 + 4] = make_float4(v[4], v[5], v[6], v[7]);
    }
  } else {
    // relu + row L2 normalize; cross-thread row reduction via xt scratch
    float v[4][8];
    float ssp[4];
#pragma unroll
    for (int i = 0; i < 4; ++i) {
      float ss = 0.f;
#pragma unroll
      for (int j = 0; j < 8; ++j) {
        float b = (BMODE == 0) ? bias_r[j] : (BMODE == 2) ? deg_r[i] * bias_r[j] : 0.f;
        float x = fmaxf(acc[i][j] + b, 0.f);
        v[i][j] = x;
        ss += x * x;
      }
      ssp[i] = ss;
    }
    __syncthreads();                       // all xt reads done; reuse as scratch
    int tg = t >> 4;
#pragma unroll
    for (int i = 0; i < 4; ++i) xt[(r0 + i) * 16 + tg] = ssp[i];
    __syncthreads();
#pragma unroll
    for (int i = 0; i < 4; ++i) {
      int node = base + r0 + i;
      if (node >= nN) continue;
      float4 p0 = *(const float4*)&xt[(r0 + i) * 16];
      float4 p1 = *(const float4*)&xt[(r0 + i) * 16 + 4];
      float4 p2 = *(const float4*)&xt[(r0 + i) * 16 + 8];
      float4 p3 = *(const float4*)&xt[(r0 + i) * 16 + 12];
      float s = p0.x + p0.y + p0.z + p0.w + p1.x + p1.y + p1.z + p1.w +
                p2.x + p2.y + p2.z + p2.w + p3.x + p3.y + p3.z + p3.w;
      float inv = 1.0f / fmaxf(sqrtf(s), 1e-12f);
      *(float4*)&Y[(size_t)node * CCH + c0] =
          make_float4(v[i][0] * inv, v[i][1] * inv, v[i][2] * inv, v[i][3] * inv);
      *(float4*)&Y[(size_t)node * CCH + c0 + 4] =
          make_float4(v[i][4] * inv, v[i][5] * inv, v[i][6] * inv, v[i][7] * inv);
    }
  }
}

// ---------------- edge aggregation (wave per node) ----------------
// A1M in: pre-relu dst-side partial (incl. bias); out: M = scale*sum_e relu(A1+A2[src]) + deg*shift
__global__ __launch_bounds__(256) void k_aggr(float* __restrict__ A1M,
                                              const float* __restrict__ A2,
                                              const int* __restrict__ rowptr,
                                              const int* __restrict__ esrc,
                                              const float* __restrict__ g,
                                              const float* __restrict__ be,
                                              const float* __restrict__ rm,
                                              const float* __restrict__ rv,
                                              int nNodes) {
  int node = blockIdx.x * 4 + (threadIdx.x >> 6);
  if (node >= nNodes) return;
  int lane = threadIdx.x & 63;
  int c = lane * 2;

  float2 a1 = *(const float2*)&A1M[(size_t)node * CCH + c];
  int r0 = rowptr[node], r1 = rowptr[node + 1];
  float s0 = 0.f, s1 = 0.f;
#pragma unroll 2
  for (int e = r0; e < r1; ++e) {
    int s = esrc[e];
    float2 vv = *(const float2*)&A2[(size_t)s * CCH + c];
    s0 += fmaxf(a1.x + vv.x, 0.f);
    s1 += fmaxf(a1.y + vv.y, 0.f);
  }
  float dn = (float)(r1 - r0);
  float sc0 = g[c] * rsqrtf(rv[c] + 1e-5f);
  float sc1 = g[c + 1] * rsqrtf(rv[c + 1] + 1e-5f);
  float sh0 = be[c] - rm[c] * sc0;
  float sh1 = be[c + 1] - rm[c + 1] * sc1;
  float2 o = make_float2(sc0 * s0 + dn * sh0, sc1 * s1 + dn * sh1);
  *(float2*)&A1M[(size_t)node * CCH + c] = o;
}

// ---------------- launch ----------------
extern "C" void kernel_launch(void* const* d_in, const int* in_sizes, int n_in,
                              void* d_out, int out_size, void* d_ws, size_t ws_size,
                              hipStream_t stream) {
  const float* x   = (const float*)d_in[0];
  const void*  ei  = d_in[1];
  const float* w1a = (const float*)d_in[2];
  const float* b1a = (const float*)d_in[3];
  const float* g1  = (const float*)d_in[4];
  const float* be1 = (const float*)d_in[5];
  const float* rm1 = (const float*)d_in[6];
  const float* rv1 = (const float*)d_in[7];
  const float* w1b = (const float*)d_in[8];
  const float* b1b = (const float*)d_in[9];
  const float* w2a = (const float*)d_in[10];
  const float* b2a = (const float*)d_in[11];
  const float* g2  = (const float*)d_in[12];
  const float* be2 = (const float*)d_in[13];
  const float* rm2 = (const float*)d_in[14];
  const float* rv2 = (const float*)d_in[15];
  const float* w2b = (const float*)d_in[16];
  const float* b2b = (const float*)d_in[17];

  const int N = in_sizes[0] / CCH;   // 50000
  const int E = in_sizes[1] / 2;     // 600000
  const size_t NC = (size_t)N * CCH;

  int* flags  = (int*)d_ws;              // 4
  int* deg    = flags + 4;               // N
  int* cnt    = deg + N;                 // N
  int* rowptr = cnt + N;                 // N+1
  int* bsum   = rowptr + N + 1;          // 256
  int* boff   = bsum + 256;              // 256
  int* esrc   = boff + 256;              // E
  uintptr_t pb = ((uintptr_t)(esrc + E) + 63) & ~(uintptr_t)63;
  float* B0 = (float*)pb;                // NC floats
  float* B1 = B0 + NC;                   // NC floats

  const int gE = (E + 255) / 256;
  const int gS = (N + 255) / 256;   // 196
  const int gG = (N + 63) / 64;     // 782
  const int gA = (N + 3) / 4;       // 12500

  k_detect<<<1, 256, 0, stream>>>((const unsigned int*)ei, flags);
  hipMemsetAsync(deg, 0, sizeof(int) * 2 * (size_t)N, stream);  // deg + cnt
  k_hist<<<gE, 256, 0, stream>>>(ei, deg, E, flags);
  k_scan1<<<gS, 256, 0, stream>>>(deg, bsum, N);
  k_scan2<<<1, 256, 0, stream>>>(bsum, boff, gS);
  k_scan3<<<gS, 256, 0, stream>>>(deg, boff, rowptr, N, E);
  k_scatter<<<gE, 256, 0, stream>>>(ei, rowptr, cnt, esrc, E, flags);

  // ---- layer 1 ----
  k_gemm<0, 0, 0><<<gG, 256, 0, stream>>>(x, w1a, b1a, nullptr, B0, N);    // A1 -> B0
  k_gemm<1, 1, 0><<<gG, 256, 0, stream>>>(x, w1a, nullptr, nullptr, B1, N); // A2 -> B1
  k_aggr<<<gA, 256, 0, stream>>>(B0, B1, rowptr, esrc, g1, be1, rm1, rv1, N); // M1 -> B0
  k_gemm<2, 2, 1><<<gG, 256, 0, stream>>>(B0, w1b, b1b, rowptr, B1, N);    // H -> B1

  // ---- layer 2 ----
  k_gemm<0, 0, 0><<<gG, 256, 0, stream>>>(B1, w2a, b2a, nullptr, B0, N);   // A1 -> B0
  k_gemm<1, 1, 0><<<gG, 256, 0, stream>>>(B1, w2a, nullptr, nullptr, B1, N); // A2 -> B1 (in-place safe)
  k_aggr<<<gA, 256, 0, stream>>>(B0, B1, rowptr, esrc, g2, be2, rm2, rv2, N); // M2 -> B0
  k_gemm<2, 2, 0><<<gG, 256, 0, stream>>>(B0, w2b, b2b, rowptr, (float*)d_out, N); // out
}

// Round 4
// 391.832 us; speedup vs baseline: 2.4543x; 1.2649x over previous
//
#include <hip/hip_runtime.h>

#define CCH 128
typedef unsigned short ushort;
typedef __attribute__((ext_vector_type(8))) short bf16x8_t;
typedef __attribute__((ext_vector_type(4))) float f32x4;

union ABu { bf16x8_t v; ushort u[8]; uint4 q; };

__device__ __forceinline__ ushort f2b(float f) {   // fp32 -> bf16 RNE
  union { float f; unsigned u; } v{f};
  unsigned r = v.u + 0x7fffu + ((v.u >> 16) & 1u);
  return (ushort)(r >> 16);
}
__device__ __forceinline__ float b2f(ushort s) {
  union { unsigned u; float f; } v{(unsigned)s << 16};
  return v.f;
}

// ---------------- edge-index width detection ----------------
__global__ void k_detect(const unsigned int* __restrict__ eiw, int* __restrict__ flags) {
  __shared__ int cz;
  int t = threadIdx.x;
  if (t == 0) cz = 0;
  __syncthreads();
  if (eiw[2 * t + 1] != 0u) atomicAdd(&cz, 1);
  __syncthreads();
  if (t == 0) flags[1] = (cz == 0) ? 1 : 0;
}

__device__ __forceinline__ int ldidx(const void* ei, size_t i, bool i64) {
  return i64 ? (int)((const long long*)ei)[i] : ((const int*)ei)[i];
}

// ---------------- CSR build ----------------
__global__ void k_hist(const void* __restrict__ ei, int* __restrict__ deg, int E,
                       const int* __restrict__ flags) {
  bool i64 = flags[1] != 0;
  int e = blockIdx.x * 256 + threadIdx.x;
  if (e < E) atomicAdd(&deg[ldidx(ei, (size_t)E + e, i64)], 1);
}

__global__ void k_scan1(const int* __restrict__ deg, int* __restrict__ bsum, int n) {
  __shared__ int s[256];
  int t = threadIdx.x, i = blockIdx.x * 256 + t;
  s[t] = (i < n) ? deg[i] : 0;
  __syncthreads();
  for (int off = 128; off > 0; off >>= 1) {
    if (t < off) s[t] += s[t + off];
    __syncthreads();
  }
  if (t == 0) bsum[blockIdx.x] = s[0];
}

__global__ void k_scan2(const int* __restrict__ bsum, int* __restrict__ boff, int nb) {
  __shared__ int s[256];
  int t = threadIdx.x;
  int v = (t < nb) ? bsum[t] : 0;
  s[t] = v; __syncthreads();
  for (int off = 1; off < 256; off <<= 1) {
    int tv = (t >= off) ? s[t - off] : 0;
    __syncthreads();
    s[t] += tv;
    __syncthreads();
  }
  if (t < nb) boff[t] = s[t] - v;
}

__global__ void k_scan3(const int* __restrict__ deg, const int* __restrict__ boff,
                        int* __restrict__ rowptr, int n, int Etot) {
  __shared__ int s[256];
  int t = threadIdx.x, i = blockIdx.x * 256 + t;
  int v = (i < n) ? deg[i] : 0;
  s[t] = v; __syncthreads();
  for (int off = 1; off < 256; off <<= 1) {
    int tv = (t >= off) ? s[t - off] : 0;
    __syncthreads();
    s[t] += tv;
    __syncthreads();
  }
  if (i < n) rowptr[i] = boff[blockIdx.x] + s[t] - v;
  if (i == 0) rowptr[n] = Etot;
}

__global__ void k_scatter(const void* __restrict__ ei, const int* __restrict__ rowptr,
                          int* __restrict__ cnt, int* __restrict__ esrc, int E,
                          const int* __restrict__ flags) {
  bool i64 = flags[1] != 0;
  int e = blockIdx.x * 256 + threadIdx.x;
  if (e < E) {
    int d = ldidx(ei, (size_t)E + e, i64);
    int s = ldidx(ei, (size_t)e, i64);
    int pos = rowptr[d] + atomicAdd(&cnt[d], 1);
    esrc[pos] = s;
  }
}

// ---------------- weight preconversion to bf16 ----------------
// Wcat[256][128]: rows 0-127 = wa[c][k]-wa[c][k+128]; rows 128-255 = wa[c][k+128]
// Wbb[128][128]  = wb
__global__ void k_wconv(const float* __restrict__ wa, const float* __restrict__ wb,
                        ushort* __restrict__ Wcat, ushort* __restrict__ Wbb) {
  int i = blockIdx.x * 256 + threadIdx.x;   // grid covers 32768
  if (i < 32768) {
    int c = i >> 7, k = i & 127;
    float v = (c < 128) ? wa[c * 256 + k] - wa[c * 256 + 128 + k]
                        : wa[(c - 128) * 256 + 128 + k];
    Wcat[i] = f2b(v);
  }
  if (i < 16384) Wbb[i] = f2b(wb[i]);
}

// ---------------- GEMM1 (fused A1|A2): [N x 128] @ Wcat^T -> A1 f32, A2 bf16 ----
// block = 4 waves x 16 rows = 64 rows; wave covers all 256 output cols.
// MFMA 16x16x32 bf16; A-frag: [m=lane&15][k=quad*8+j]; B-frag: Wcat row n, 8 contig k.
template <typename TIN>   // float (layer1 x) or ushort (layer2 H bf16)
__global__ __launch_bounds__(256) void k_gemm1(const TIN* __restrict__ X,
                                               const ushort* __restrict__ Wcat,
                                               const float* __restrict__ bias,
                                               float* __restrict__ A1,
                                               ushort* __restrict__ A2, int nN) {
  const int t = threadIdx.x;
  const int wave = t >> 6, lane = t & 63;
  const int ln = lane & 15, quad = lane >> 4;
  const int rowbase = blockIdx.x * 64 + wave * 16;
  const int arow = rowbase + ln;
  const bool aok = arow < nN;

  // load 4 A-frags (whole K=128 for this lane's row)
  ABu a[4];
#pragma unroll
  for (int kk = 0; kk < 4; ++kk) {
    if (aok) {
      if constexpr (sizeof(TIN) == 4) {
        const float* xp = (const float*)X + (size_t)arow * CCH + kk * 32 + quad * 8;
        float4 f0 = *(const float4*)xp;
        float4 f1 = *(const float4*)(xp + 4);
        a[kk].u[0] = f2b(f0.x); a[kk].u[1] = f2b(f0.y);
        a[kk].u[2] = f2b(f0.z); a[kk].u[3] = f2b(f0.w);
        a[kk].u[4] = f2b(f1.x); a[kk].u[5] = f2b(f1.y);
        a[kk].u[6] = f2b(f1.z); a[kk].u[7] = f2b(f1.w);
      } else {
        a[kk].q = *(const uint4*)((const ushort*)X + (size_t)arow * CCH + kk * 32 + quad * 8);
      }
    } else {
      a[kk].q = make_uint4(0, 0, 0, 0);
    }
  }

  f32x4 acc[16];
#pragma unroll
  for (int s = 0; s < 16; ++s) acc[s] = (f32x4){0.f, 0.f, 0.f, 0.f};

  const ushort* wbase = Wcat + (size_t)ln * CCH + quad * 8;
#pragma unroll
  for (int s = 0; s < 16; ++s) {
#pragma unroll
    for (int kk = 0; kk < 4; ++kk) {
      ABu b;
      b.q = *(const uint4*)(wbase + (size_t)s * 16 * CCH + kk * 32);
      acc[s] = __builtin_amdgcn_mfma_f32_16x16x32_bf16(a[kk].v, b.v, acc[s], 0, 0, 0);
    }
  }

  // epilogue: C/D row = quad*4+reg, col = ln (within 16x16 tile s)
#pragma unroll
  for (int s = 0; s < 16; ++s) {
    int col = s * 16 + ln;
    float bv = (s < 8) ? bias[col] : 0.f;
#pragma unroll
    for (int r = 0; r < 4; ++r) {
      int row = rowbase + quad * 4 + r;
      if (row >= nN) continue;
      float v = acc[s][r];
      if (s < 8) A1[(size_t)row * CCH + col] = v + bv;
      else       A2[(size_t)row * CCH + (col - 128)] = f2b(v);
    }
  }
}

// ---------------- GEMM2: out = M @ Wb^T + deg*bias; EPI 0: f32 store, 1: relu+L2norm -> bf16
template <int EPI>
__global__ __launch_bounds__(256) void k_gemm2(const float* __restrict__ M,
                                               const ushort* __restrict__ Wb,
                                               const float* __restrict__ bias,
                                               const int* __restrict__ deg,
                                               void* __restrict__ OUT, int nN) {
  const int t = threadIdx.x;
  const int wave = t >> 6, lane = t & 63;
  const int ln = lane & 15, quad = lane >> 4;
  const int rowbase = blockIdx.x * 64 + wave * 16;
  const int arow = rowbase + ln;
  const bool aok = arow < nN;

  ABu a[4];
#pragma unroll
  for (int kk = 0; kk < 4; ++kk) {
    if (aok) {
      const float* xp = M + (size_t)arow * CCH + kk * 32 + quad * 8;
      float4 f0 = *(const float4*)xp;
      float4 f1 = *(const float4*)(xp + 4);
      a[kk].u[0] = f2b(f0.x); a[kk].u[1] = f2b(f0.y);
      a[kk].u[2] = f2b(f0.z); a[kk].u[3] = f2b(f0.w);
      a[kk].u[4] = f2b(f1.x); a[kk].u[5] = f2b(f1.y);
      a[kk].u[6] = f2b(f1.z); a[kk].u[7] = f2b(f1.w);
    } else {
      a[kk].q = make_uint4(0, 0, 0, 0);
    }
  }

  f32x4 acc[8];
#pragma unroll
  for (int s = 0; s < 8; ++s) acc[s] = (f32x4){0.f, 0.f, 0.f, 0.f};

  const ushort* wbase = Wb + (size_t)ln * CCH + quad * 8;
#pragma unroll
  for (int s = 0; s < 8; ++s) {
#pragma unroll
    for (int kk = 0; kk < 4; ++kk) {
      ABu b;
      b.q = *(const uint4*)(wbase + (size_t)s * 16 * CCH + kk * 32);
      acc[s] = __builtin_amdgcn_mfma_f32_16x16x32_bf16(a[kk].v, b.v, acc[s], 0, 0, 0);
    }
  }

  float biasv[8];
#pragma unroll
  for (int s = 0; s < 8; ++s) biasv[s] = bias[s * 16 + ln];
  float degv[4];
#pragma unroll
  for (int r = 0; r < 4; ++r) {
    int row = rowbase + quad * 4 + r;
    degv[r] = (row < nN) ? (float)deg[row] : 0.f;
  }

  if (EPI == 0) {
    float* out = (float*)OUT;
#pragma unroll
    for (int s = 0; s < 8; ++s) {
      int col = s * 16 + ln;
#pragma unroll
      for (int r = 0; r < 4; ++r) {
        int row = rowbase + quad * 4 + r;
        if (row >= nN) continue;
        out[(size_t)row * CCH + col] = acc[s][r] + degv[r] * biasv[s];
      }
    }
  } else {
    ushort* out = (ushort*)OUT;
#pragma unroll
    for (int r = 0; r < 4; ++r) {
      int row = rowbase + quad * 4 + r;
      float vals[8];
      float ss = 0.f;
#pragma unroll
      for (int s = 0; s < 8; ++s) {
        float v = fmaxf(acc[s][r] + degv[r] * biasv[s], 0.f);
        vals[s] = v;
        ss += v * v;
      }
      // row spans the 16 lanes of this quad: butterfly within 16-lane group
      ss += __shfl_xor(ss, 1, 64);
      ss += __shfl_xor(ss, 2, 64);
      ss += __shfl_xor(ss, 4, 64);
      ss += __shfl_xor(ss, 8, 64);
      float inv = 1.0f / fmaxf(sqrtf(ss), 1e-12f);
      if (row < nN) {
#pragma unroll
        for (int s = 0; s < 8; ++s)
          out[(size_t)row * CCH + s * 16 + ln] = f2b(vals[s] * inv);
      }
    }
  }
}

// ---------------- edge aggregation (wave per node, A2 bf16) ----------------
__global__ __launch_bounds__(256) void k_aggr(float* __restrict__ A1M,
                                              const ushort* __restrict__ A2,
                                              const int* __restrict__ rowptr,
                                              const int* __restrict__ esrc,
                                              const float* __restrict__ g,
                                              const float* __restrict__ be,
                                              const float* __restrict__ rm,
                                              const float* __restrict__ rv,
                                              int nNodes) {
  int node = blockIdx.x * 4 + (threadIdx.x >> 6);
  if (node >= nNodes) return;
  int lane = threadIdx.x & 63;
  int c = lane * 2;

  float2 a1 = *(const float2*)&A1M[(size_t)node * CCH + c];
  int r0 = rowptr[node], r1 = rowptr[node + 1];
  float s0 = 0.f, s1 = 0.f;
  int e = r0;
  for (; e + 1 < r1; e += 2) {
    int sA = esrc[e], sB = esrc[e + 1];
    unsigned wA = *(const unsigned*)&A2[(size_t)sA * CCH + c];
    unsigned wB = *(const unsigned*)&A2[(size_t)sB * CCH + c];
    s0 += fmaxf(a1.x + b2f((ushort)wA), 0.f);
    s1 += fmaxf(a1.y + b2f((ushort)(wA >> 16)), 0.f);
    s0 += fmaxf(a1.x + b2f((ushort)wB), 0.f);
    s1 += fmaxf(a1.y + b2f((ushort)(wB >> 16)), 0.f);
  }
  if (e < r1) {
    int sA = esrc[e];
    unsigned wA = *(const unsigned*)&A2[(size_t)sA * CCH + c];
    s0 += fmaxf(a1.x + b2f((ushort)wA), 0.f);
    s1 += fmaxf(a1.y + b2f((ushort)(wA >> 16)), 0.f);
  }
  float dn = (float)(r1 - r0);
  float sc0 = g[c] * rsqrtf(rv[c] + 1e-5f);
  float sc1 = g[c + 1] * rsqrtf(rv[c + 1] + 1e-5f);
  float sh0 = be[c] - rm[c] * sc0;
  float sh1 = be[c + 1] - rm[c + 1] * sc1;
  float2 o = make_float2(sc0 * s0 + dn * sh0, sc1 * s1 + dn * sh1);
  *(float2*)&A1M[(size_t)node * CCH + c] = o;
}

// ---------------- launch ----------------
extern "C" void kernel_launch(void* const* d_in, const int* in_sizes, int n_in,
                              void* d_out, int out_size, void* d_ws, size_t ws_size,
                              hipStream_t stream) {
  const float* x   = (const float*)d_in[0];
  const void*  ei  = d_in[1];
  const float* w1a = (const float*)d_in[2];
  const float* b1a = (const float*)d_in[3];
  const float* g1  = (const float*)d_in[4];
  const float* be1 = (const float*)d_in[5];
  const float* rm1 = (const float*)d_in[6];
  const float* rv1 = (const float*)d_in[7];
  const float* w1b = (const float*)d_in[8];
  const float* b1b = (const float*)d_in[9];
  const float* w2a = (const float*)d_in[10];
  const float* b2a = (const float*)d_in[11];
  const float* g2  = (const float*)d_in[12];
  const float* be2 = (const float*)d_in[13];
  const float* rm2 = (const float*)d_in[14];
  const float* rv2 = (const float*)d_in[15];
  const float* w2b = (const float*)d_in[16];
  const float* b2b = (const float*)d_in[17];

  const int N = in_sizes[0] / CCH;   // 50000
  const int E = in_sizes[1] / 2;     // 600000
  const size_t NC = (size_t)N * CCH;

  int* flags  = (int*)d_ws;              // 4
  int* deg    = flags + 4;               // N
  int* cnt    = deg + N;                 // N
  int* rowptr = cnt + N;                 // N+1
  int* bsum   = rowptr + N + 1;          // 256
  int* boff   = bsum + 256;              // 256
  int* esrc   = boff + 256;              // E
  uintptr_t pw = ((uintptr_t)(esrc + E) + 63) & ~(uintptr_t)63;
  ushort* Wcat1 = (ushort*)pw;           // 256*128
  ushort* Wcat2 = Wcat1 + 32768;         // 256*128
  ushort* Wb1   = Wcat2 + 32768;         // 128*128
  ushort* Wb2   = Wb1 + 16384;           // 128*128
  uintptr_t pb = ((uintptr_t)(Wb2 + 16384) + 63) & ~(uintptr_t)63;
  float*  B0 = (float*)pb;               // NC f32   (A1 / M)
  ushort* B1 = (ushort*)(B0 + NC);       // NC bf16  (A2)
  ushort* B2 = B1 + NC;                  // NC bf16  (H)
  // total ≈ 3.4 MB + 0.2 MB + 25.6 + 12.8 + 12.8 ≈ 55 MB

  const int gE = (E + 255) / 256;
  const int gS = (N + 255) / 256;
  const int gG = (N + 63) / 64;     // 782
  const int gA = (N + 3) / 4;       // 12500

  k_detect<<<1, 256, 0, stream>>>((const unsigned int*)ei, flags);
  hipMemsetAsync(deg, 0, sizeof(int) * 2 * (size_t)N, stream);
  k_wconv<<<128, 256, 0, stream>>>(w1a, w1b, Wcat1, Wb1);
  k_wconv<<<128, 256, 0, stream>>>(w2a, w2b, Wcat2, Wb2);
  k_hist<<<gE, 256, 0, stream>>>(ei, deg, E, flags);
  k_scan1<<<gS, 256, 0, stream>>>(deg, bsum, N);
  k_scan2<<<1, 256, 0, stream>>>(bsum, boff, gS);
  k_scan3<<<gS, 256, 0, stream>>>(deg, boff, rowptr, N, E);
  k_scatter<<<gE, 256, 0, stream>>>(ei, rowptr, cnt, esrc, E, flags);

  // ---- layer 1 ----
  k_gemm1<float><<<gG, 256, 0, stream>>>(x, Wcat1, b1a, B0, B1, N);            // A1->B0, A2->B1
  k_aggr<<<gA, 256, 0, stream>>>(B0, B1, rowptr, esrc, g1, be1, rm1, rv1, N);  // M1 -> B0
  k_gemm2<1><<<gG, 256, 0, stream>>>(B0, Wb1, b1b, deg, B2, N);                // H (bf16) -> B2

  // ---- layer 2 ----
  k_gemm1<ushort><<<gG, 256, 0, stream>>>(B2, Wcat2, b2a, B0, B1, N);          // A1->B0, A2->B1
  k_aggr<<<gA, 256, 0, stream>>>(B0, B1, rowptr, esrc, g2, be2, rm2, rv2, N);  // M2 -> B0
  k_gemm2<0><<<gG, 256, 0, stream>>>(B0, Wb2, b2b, deg, d_out, N);             // out f32
}

// Round 5
// 378.505 us; speedup vs baseline: 2.5407x; 1.0352x over previous
//
#include <hip/hip_runtime.h>

#define CCH 128
typedef unsigned short ushort;
typedef __attribute__((ext_vector_type(8))) short bf16x8_t;
typedef __attribute__((ext_vector_type(4))) float f32x4;

union ABu { bf16x8_t v; ushort u[8]; uint4 q; };

__device__ __forceinline__ ushort f2b(float f) {   // fp32 -> bf16 RNE
  union { float f; unsigned u; } v{f};
  unsigned r = v.u + 0x7fffu + ((v.u >> 16) & 1u);
  return (ushort)(r >> 16);
}
__device__ __forceinline__ float b2f(ushort s) {
  union { unsigned u; float f; } v{(unsigned)s << 16};
  return v.f;
}

// ---------------- edge-index width detection ----------------
__global__ void k_detect(const unsigned int* __restrict__ eiw, int* __restrict__ flags) {
  __shared__ int cz;
  int t = threadIdx.x;
  if (t == 0) cz = 0;
  __syncthreads();
  if (eiw[2 * t + 1] != 0u) atomicAdd(&cz, 1);
  __syncthreads();
  if (t == 0) flags[1] = (cz == 0) ? 1 : 0;
}

__device__ __forceinline__ int ldidx(const void* ei, size_t i, bool i64) {
  return i64 ? (int)((const long long*)ei)[i] : ((const int*)ei)[i];
}

// ---------------- CSR build ----------------
__global__ void k_hist(const void* __restrict__ ei, int* __restrict__ deg, int E,
                       const int* __restrict__ flags) {
  bool i64 = flags[1] != 0;
  int e = blockIdx.x * 256 + threadIdx.x;
  if (e < E) atomicAdd(&deg[ldidx(ei, (size_t)E + e, i64)], 1);
}

__global__ void k_scan1(const int* __restrict__ deg, int* __restrict__ bsum, int n) {
  __shared__ int s[256];
  int t = threadIdx.x, i = blockIdx.x * 256 + t;
  s[t] = (i < n) ? deg[i] : 0;
  __syncthreads();
  for (int off = 128; off > 0; off >>= 1) {
    if (t < off) s[t] += s[t + off];
    __syncthreads();
  }
  if (t == 0) bsum[blockIdx.x] = s[0];
}

__global__ void k_scan2(const int* __restrict__ bsum, int* __restrict__ boff, int nb) {
  __shared__ int s[256];
  int t = threadIdx.x;
  int v = (t < nb) ? bsum[t] : 0;
  s[t] = v; __syncthreads();
  for (int off = 1; off < 256; off <<= 1) {
    int tv = (t >= off) ? s[t - off] : 0;
    __syncthreads();
    s[t] += tv;
    __syncthreads();
  }
  if (t < nb) boff[t] = s[t] - v;
}

__global__ void k_scan3(const int* __restrict__ deg, const int* __restrict__ boff,
                        int* __restrict__ rowptr, int n, int Etot) {
  __shared__ int s[256];
  int t = threadIdx.x, i = blockIdx.x * 256 + t;
  int v = (i < n) ? deg[i] : 0;
  s[t] = v; __syncthreads();
  for (int off = 1; off < 256; off <<= 1) {
    int tv = (t >= off) ? s[t - off] : 0;
    __syncthreads();
    s[t] += tv;
    __syncthreads();
  }
  if (i < n) rowptr[i] = boff[blockIdx.x] + s[t] - v;
  if (i == 0) rowptr[n] = Etot;
}

__global__ void k_scatter(const void* __restrict__ ei, const int* __restrict__ rowptr,
                          int* __restrict__ cnt, int* __restrict__ esrc, int E,
                          const int* __restrict__ flags) {
  bool i64 = flags[1] != 0;
  int e = blockIdx.x * 256 + threadIdx.x;
  if (e < E) {
    int d = ldidx(ei, (size_t)E + e, i64);
    int s = ldidx(ei, (size_t)e, i64);
    int pos = rowptr[d] + atomicAdd(&cnt[d], 1);
    esrc[pos] = s;
  }
}

// ---------------- weight preconversion to bf16 ----------------
__global__ void k_wconv(const float* __restrict__ wa, const float* __restrict__ wb,
                        ushort* __restrict__ Wcat, ushort* __restrict__ Wbb) {
  int i = blockIdx.x * 256 + threadIdx.x;   // grid covers 32768
  if (i < 32768) {
    int c = i >> 7, k = i & 127;
    float v = (c < 128) ? wa[c * 256 + k] - wa[c * 256 + 128 + k]
                        : wa[(c - 128) * 256 + 128 + k];
    Wcat[i] = f2b(v);
  }
  if (i < 16384) Wbb[i] = f2b(wb[i]);
}

// ---------------- GEMM1 (layer1, fused A1|A2): x(f32) @ Wcat^T -> A1 f32, A2 bf16 ----
__global__ __launch_bounds__(256) void k_gemm1(const float* __restrict__ X,
                                               const ushort* __restrict__ Wcat,
                                               const float* __restrict__ bias,
                                               float* __restrict__ A1,
                                               ushort* __restrict__ A2, int nN) {
  const int t = threadIdx.x;
  const int wave = t >> 6, lane = t & 63;
  const int ln = lane & 15, quad = lane >> 4;
  const int rowbase = blockIdx.x * 64 + wave * 16;
  const int arow = rowbase + ln;
  const bool aok = arow < nN;

  ABu a[4];
#pragma unroll
  for (int kk = 0; kk < 4; ++kk) {
    if (aok) {
      const float* xp = X + (size_t)arow * CCH + kk * 32 + quad * 8;
      float4 f0 = *(const float4*)xp;
      float4 f1 = *(const float4*)(xp + 4);
      a[kk].u[0] = f2b(f0.x); a[kk].u[1] = f2b(f0.y);
      a[kk].u[2] = f2b(f0.z); a[kk].u[3] = f2b(f0.w);
      a[kk].u[4] = f2b(f1.x); a[kk].u[5] = f2b(f1.y);
      a[kk].u[6] = f2b(f1.z); a[kk].u[7] = f2b(f1.w);
    } else {
      a[kk].q = make_uint4(0, 0, 0, 0);
    }
  }

  f32x4 acc[16];
#pragma unroll
  for (int s = 0; s < 16; ++s) acc[s] = (f32x4){0.f, 0.f, 0.f, 0.f};

  const ushort* wbase = Wcat + (size_t)ln * CCH + quad * 8;
#pragma unroll
  for (int s = 0; s < 16; ++s) {
#pragma unroll
    for (int kk = 0; kk < 4; ++kk) {
      ABu b;
      b.q = *(const uint4*)(wbase + (size_t)s * 16 * CCH + kk * 32);
      acc[s] = __builtin_amdgcn_mfma_f32_16x16x32_bf16(a[kk].v, b.v, acc[s], 0, 0, 0);
    }
  }

#pragma unroll
  for (int s = 0; s < 16; ++s) {
    int col = s * 16 + ln;
    float bv = (s < 8) ? bias[col] : 0.f;
#pragma unroll
    for (int r = 0; r < 4; ++r) {
      int row = rowbase + quad * 4 + r;
      if (row >= nN) continue;
      float v = acc[s][r];
      if (s < 8) A1[(size_t)row * CCH + col] = v + bv;
      else       A2[(size_t)row * CCH + (col - 128)] = f2b(v);
    }
  }
}

// ---------------- edge aggregation v2 (wave/node, half-wave = one edge) ----------------
// M(bf16) = scale * sum_e relu(A1 + A2[src]) + deg*shift
__global__ __launch_bounds__(256) void k_aggr(const float* __restrict__ A1,
                                              const ushort* __restrict__ A2,
                                              const int* __restrict__ rowptr,
                                              const int* __restrict__ esrc,
                                              const float* __restrict__ g,
                                              const float* __restrict__ be,
                                              const float* __restrict__ rm,
                                              const float* __restrict__ rv,
                                              ushort* __restrict__ M, int nNodes) {
  int node = blockIdx.x * 4 + (threadIdx.x >> 6);
  if (node >= nNodes) return;
  int lane = threadIdx.x & 63;
  int half = lane >> 5;           // which edge of a pair
  int c = (lane & 31) * 4;        // 4 channels per lane

  float4 a1 = *(const float4*)&A1[(size_t)node * CCH + c];
  int r0 = rowptr[node], r1 = rowptr[node + 1];
  float s0 = 0.f, s1 = 0.f, s2 = 0.f, s3 = 0.f;

  int e = r0 + half;
  for (; e + 2 < r1; e += 4) {           // 2 edges per half-wave iter (4/wave in flight)
    int sA = esrc[e], sB = esrc[e + 2];
    uint2 wA = *(const uint2*)&A2[(size_t)sA * CCH + c];
    uint2 wB = *(const uint2*)&A2[(size_t)sB * CCH + c];
    s0 += fmaxf(a1.x + b2f((ushort)wA.x), 0.f);
    s1 += fmaxf(a1.y + b2f((ushort)(wA.x >> 16)), 0.f);
    s2 += fmaxf(a1.z + b2f((ushort)wA.y), 0.f);
    s3 += fmaxf(a1.w + b2f((ushort)(wA.y >> 16)), 0.f);
    s0 += fmaxf(a1.x + b2f((ushort)wB.x), 0.f);
    s1 += fmaxf(a1.y + b2f((ushort)(wB.x >> 16)), 0.f);
    s2 += fmaxf(a1.z + b2f((ushort)wB.y), 0.f);
    s3 += fmaxf(a1.w + b2f((ushort)(wB.y >> 16)), 0.f);
  }
  for (; e < r1; e += 2) {
    int sA = esrc[e];
    uint2 wA = *(const uint2*)&A2[(size_t)sA * CCH + c];
    s0 += fmaxf(a1.x + b2f((ushort)wA.x), 0.f);
    s1 += fmaxf(a1.y + b2f((ushort)(wA.x >> 16)), 0.f);
    s2 += fmaxf(a1.z + b2f((ushort)wA.y), 0.f);
    s3 += fmaxf(a1.w + b2f((ushort)(wA.y >> 16)), 0.f);
  }
  // combine the two halves
  s0 += __shfl_xor(s0, 32, 64);
  s1 += __shfl_xor(s1, 32, 64);
  s2 += __shfl_xor(s2, 32, 64);
  s3 += __shfl_xor(s3, 32, 64);

  if (half == 0) {
    float dn = (float)(r1 - r0);
    float o[4];
#pragma unroll
    for (int j = 0; j < 4; ++j) {
      float sc = g[c + j] * rsqrtf(rv[c + j] + 1e-5f);
      float sh = be[c + j] - rm[c + j] * sc;
      float sv = (j == 0) ? s0 : (j == 1) ? s1 : (j == 2) ? s2 : s3;
      o[j] = sc * sv + dn * sh;
    }
    uint2 p;
    p.x = (unsigned)f2b(o[0]) | ((unsigned)f2b(o[1]) << 16);
    p.y = (unsigned)f2b(o[2]) | ((unsigned)f2b(o[3]) << 16);
    *(uint2*)&M[(size_t)node * CCH + c] = p;
  }
}

// ---------------- fused: H = l2norm(relu(M@Wb^T + deg*bb)); then A1|A2 = H @ Wcat2^T ----
#define HSTRIDE 136   // ushorts; 272B rows: 16B-aligned, quad-spread banks
__global__ __launch_bounds__(256) void k_fuse(const ushort* __restrict__ M,
                                              const ushort* __restrict__ Wb,
                                              const float* __restrict__ bb,
                                              const int* __restrict__ deg,
                                              const ushort* __restrict__ Wcat,
                                              const float* __restrict__ ba2,
                                              float* __restrict__ A1,
                                              ushort* __restrict__ A2, int nN) {
  __shared__ ushort hs[4 * 16 * HSTRIDE];
  const int t = threadIdx.x;
  const int wave = t >> 6, lane = t & 63;
  const int ln = lane & 15, quad = lane >> 4;
  const int rowbase = blockIdx.x * 64 + wave * 16;
  ushort* hw = &hs[wave * 16 * HSTRIDE];

  // ---- phase 1: H tile (16 rows x 128 cols) ----
  {
    const int arow = rowbase + ln;
    ABu a[4];
#pragma unroll
    for (int kk = 0; kk < 4; ++kk)
      a[kk].q = (arow < nN) ? *(const uint4*)(M + (size_t)arow * CCH + kk * 32 + quad * 8)
                            : make_uint4(0, 0, 0, 0);
    f32x4 acc[8];
#pragma unroll
    for (int s = 0; s < 8; ++s) acc[s] = (f32x4){0.f, 0.f, 0.f, 0.f};
    const ushort* wbase = Wb + (size_t)ln * CCH + quad * 8;
#pragma unroll
    for (int s = 0; s < 8; ++s) {
#pragma unroll
      for (int kk = 0; kk < 4; ++kk) {
        ABu b;
        b.q = *(const uint4*)(wbase + (size_t)s * 16 * CCH + kk * 32);
        acc[s] = __builtin_amdgcn_mfma_f32_16x16x32_bf16(a[kk].v, b.v, acc[s], 0, 0, 0);
      }
    }
    float biasv[8];
#pragma unroll
    for (int s = 0; s < 8; ++s) biasv[s] = bb[s * 16 + ln];
    float degv[4];
#pragma unroll
    for (int r = 0; r < 4; ++r) {
      int row = rowbase + quad * 4 + r;
      degv[r] = (row < nN) ? (float)deg[row] : 0.f;
    }
#pragma unroll
    for (int r = 0; r < 4; ++r) {
      float vals[8];
      float ss = 0.f;
#pragma unroll
      for (int s = 0; s < 8; ++s) {
        float v = fmaxf(acc[s][r] + degv[r] * biasv[s], 0.f);
        vals[s] = v;
        ss += v * v;
      }
      ss += __shfl_xor(ss, 1, 64);
      ss += __shfl_xor(ss, 2, 64);
      ss += __shfl_xor(ss, 4, 64);
      ss += __shfl_xor(ss, 8, 64);
      float inv = 1.0f / fmaxf(sqrtf(ss), 1e-12f);
      int lr = quad * 4 + r;
#pragma unroll
      for (int s = 0; s < 8; ++s) hw[lr * HSTRIDE + s * 16 + ln] = f2b(vals[s] * inv);
    }
  }
  // same-wave LDS RAW: compiler inserts lgkmcnt wait; no barrier needed (private region)

  // ---- phase 2: A1|A2 = H @ Wcat2^T ----
  ABu a[4];
#pragma unroll
  for (int kk = 0; kk < 4; ++kk)
    a[kk].q = *(const uint4*)&hw[ln * HSTRIDE + kk * 32 + quad * 8];

  f32x4 acc[16];
#pragma unroll
  for (int s = 0; s < 16; ++s) acc[s] = (f32x4){0.f, 0.f, 0.f, 0.f};
  const ushort* wbase = Wcat + (size_t)ln * CCH + quad * 8;
#pragma unroll
  for (int s = 0; s < 16; ++s) {
#pragma unroll
    for (int kk = 0; kk < 4; ++kk) {
      ABu b;
      b.q = *(const uint4*)(wbase + (size_t)s * 16 * CCH + kk * 32);
      acc[s] = __builtin_amdgcn_mfma_f32_16x16x32_bf16(a[kk].v, b.v, acc[s], 0, 0, 0);
    }
  }
#pragma unroll
  for (int s = 0; s < 16; ++s) {
    int col = s * 16 + ln;
    float bv = (s < 8) ? ba2[col] : 0.f;
#pragma unroll
    for (int r = 0; r < 4; ++r) {
      int row = rowbase + quad * 4 + r;
      if (row >= nN) continue;
      float v = acc[s][r];
      if (s < 8) A1[(size_t)row * CCH + col] = v + bv;
      else       A2[(size_t)row * CCH + (col - 128)] = f2b(v);
    }
  }
}

// ---------------- final GEMM: out = M2 @ Wb2^T + deg*bias (f32 out) ----------------
__global__ __launch_bounds__(256) void k_gemm2f(const ushort* __restrict__ M,
                                                const ushort* __restrict__ Wb,
                                                const float* __restrict__ bias,
                                                const int* __restrict__ deg,
                                                float* __restrict__ OUT, int nN) {
  const int t = threadIdx.x;
  const int wave = t >> 6, lane = t & 63;
  const int ln = lane & 15, quad = lane >> 4;
  const int rowbase = blockIdx.x * 64 + wave * 16;
  const int arow = rowbase + ln;

  ABu a[4];
#pragma unroll
  for (int kk = 0; kk < 4; ++kk)
    a[kk].q = (arow < nN) ? *(const uint4*)(M + (size_t)arow * CCH + kk * 32 + quad * 8)
                          : make_uint4(0, 0, 0, 0);

  f32x4 acc[8];
#pragma unroll
  for (int s = 0; s < 8; ++s) acc[s] = (f32x4){0.f, 0.f, 0.f, 0.f};
  const ushort* wbase = Wb + (size_t)ln * CCH + quad * 8;
#pragma unroll
  for (int s = 0; s < 8; ++s) {
#pragma unroll
    for (int kk = 0; kk < 4; ++kk) {
      ABu b;
      b.q = *(const uint4*)(wbase + (size_t)s * 16 * CCH + kk * 32);
      acc[s] = __builtin_amdgcn_mfma_f32_16x16x32_bf16(a[kk].v, b.v, acc[s], 0, 0, 0);
    }
  }

  float biasv[8];
#pragma unroll
  for (int s = 0; s < 8; ++s) biasv[s] = bias[s * 16 + ln];
#pragma unroll
  for (int s = 0; s < 8; ++s) {
    int col = s * 16 + ln;
#pragma unroll
    for (int r = 0; r < 4; ++r) {
      int row = rowbase + quad * 4 + r;
      if (row >= nN) continue;
      OUT[(size_t)row * CCH + col] = acc[s][r] + (float)deg[row] * biasv[s];
    }
  }
}

// ---------------- launch ----------------
extern "C" void kernel_launch(void* const* d_in, const int* in_sizes, int n_in,
                              void* d_out, int out_size, void* d_ws, size_t ws_size,
                              hipStream_t stream) {
  const float* x   = (const float*)d_in[0];
  const void*  ei  = d_in[1];
  const float* w1a = (const float*)d_in[2];
  const float* b1a = (const float*)d_in[3];
  const float* g1  = (const float*)d_in[4];
  const float* be1 = (const float*)d_in[5];
  const float* rm1 = (const float*)d_in[6];
  const float* rv1 = (const float*)d_in[7];
  const float* w1b = (const float*)d_in[8];
  const float* b1b = (const float*)d_in[9];
  const float* w2a = (const float*)d_in[10];
  const float* b2a = (const float*)d_in[11];
  const float* g2  = (const float*)d_in[12];
  const float* be2 = (const float*)d_in[13];
  const float* rm2 = (const float*)d_in[14];
  const float* rv2 = (const float*)d_in[15];
  const float* w2b = (const float*)d_in[16];
  const float* b2b = (const float*)d_in[17];

  const int N = in_sizes[0] / CCH;   // 50000
  const int E = in_sizes[1] / 2;     // 600000
  const size_t NC = (size_t)N * CCH;

  int* flags  = (int*)d_ws;              // 4
  int* deg    = flags + 4;               // N
  int* cnt    = deg + N;                 // N
  int* rowptr = cnt + N;                 // N+1
  int* bsum   = rowptr + N + 1;          // 256
  int* boff   = bsum + 256;              // 256
  int* esrc   = boff + 256;              // E
  uintptr_t pw = ((uintptr_t)(esrc + E) + 63) & ~(uintptr_t)63;
  ushort* Wcat1 = (ushort*)pw;           // 256*128
  ushort* Wcat2 = Wcat1 + 32768;         // 256*128
  ushort* Wb1   = Wcat2 + 32768;         // 128*128
  ushort* Wb2   = Wb1 + 16384;           // 128*128
  uintptr_t pb = ((uintptr_t)(Wb2 + 16384) + 63) & ~(uintptr_t)63;
  float*  B0 = (float*)pb;               // NC f32   (A1)
  ushort* B1 = (ushort*)(B0 + NC);       // NC bf16  (A2)
  ushort* MB = B1 + NC;                  // NC bf16  (M)
  // total ≈ 3.4 MB + 0.2 MB + 25.6 + 12.8 + 12.8 ≈ 55 MB

  const int gE = (E + 255) / 256;
  const int gS = (N + 255) / 256;
  const int gG = (N + 63) / 64;     // 782
  const int gA = (N + 3) / 4;       // 12500

  k_detect<<<1, 256, 0, stream>>>((const unsigned int*)ei, flags);
  hipMemsetAsync(deg, 0, sizeof(int) * 2 * (size_t)N, stream);
  k_wconv<<<128, 256, 0, stream>>>(w1a, w1b, Wcat1, Wb1);
  k_wconv<<<128, 256, 0, stream>>>(w2a, w2b, Wcat2, Wb2);
  k_hist<<<gE, 256, 0, stream>>>(ei, deg, E, flags);
  k_scan1<<<gS, 256, 0, stream>>>(deg, bsum, N);
  k_scan2<<<1, 256, 0, stream>>>(bsum, boff, gS);
  k_scan3<<<gS, 256, 0, stream>>>(deg, boff, rowptr, N, E);
  k_scatter<<<gE, 256, 0, stream>>>(ei, rowptr, cnt, esrc, E, flags);

  // ---- layer 1 ----
  k_gemm1<<<gG, 256, 0, stream>>>(x, Wcat1, b1a, B0, B1, N);                        // A1->B0, A2->B1
  k_aggr<<<gA, 256, 0, stream>>>(B0, B1, rowptr, esrc, g1, be1, rm1, rv1, MB, N);   // M1 -> MB
  // ---- H (in-reg) + layer-2 conv ----
  k_fuse<<<gG, 256, 0, stream>>>(MB, Wb1, b1b, deg, Wcat2, b2a, B0, B1, N);         // A1->B0, A2->B1
  k_aggr<<<gA, 256, 0, stream>>>(B0, B1, rowptr, esrc, g2, be2, rm2, rv2, MB, N);   // M2 -> MB
  k_gemm2f<<<gG, 256, 0, stream>>>(MB, Wb2, b2b, deg, (float*)d_out, N);            // out f32
}

// Round 6
// 313.390 us; speedup vs baseline: 3.0686x; 1.2078x over previous
//
#include <hip/hip_runtime.h>

#define CCH 128
#define WPAD 136   // LDS row stride in ushorts: 272B -> bank 4*(ln+quad)%32, balanced
typedef unsigned short ushort;
typedef __attribute__((ext_vector_type(8))) short bf16x8_t;
typedef __attribute__((ext_vector_type(4))) float f32x4;

union ABu { bf16x8_t v; ushort u[8]; uint4 q; };

__device__ __forceinline__ ushort f2b(float f) {   // fp32 -> bf16 RNE
  union { float f; unsigned u; } v{f};
  unsigned r = v.u + 0x7fffu + ((v.u >> 16) & 1u);
  return (ushort)(r >> 16);
}
__device__ __forceinline__ float b2f(ushort s) {
  union { unsigned u; float f; } v{(unsigned)s << 16};
  return v.f;
}

// ---------------- edge-index width detection ----------------
__global__ void k_detect(const unsigned int* __restrict__ eiw, int* __restrict__ flags) {
  __shared__ int cz;
  int t = threadIdx.x;
  if (t == 0) cz = 0;
  __syncthreads();
  if (eiw[2 * t + 1] != 0u) atomicAdd(&cz, 1);
  __syncthreads();
  if (t == 0) flags[1] = (cz == 0) ? 1 : 0;
}

__device__ __forceinline__ int ldidx(const void* ei, size_t i, bool i64) {
  return i64 ? (int)((const long long*)ei)[i] : ((const int*)ei)[i];
}

// ---------------- CSR build ----------------
__global__ void k_hist(const void* __restrict__ ei, int* __restrict__ deg, int E,
                       const int* __restrict__ flags) {
  bool i64 = flags[1] != 0;
  int e = blockIdx.x * 256 + threadIdx.x;
  if (e < E) atomicAdd(&deg[ldidx(ei, (size_t)E + e, i64)], 1);
}

__global__ void k_scan1(const int* __restrict__ deg, int* __restrict__ bsum, int n) {
  __shared__ int s[256];
  int t = threadIdx.x, i = blockIdx.x * 256 + t;
  s[t] = (i < n) ? deg[i] : 0;
  __syncthreads();
  for (int off = 128; off > 0; off >>= 1) {
    if (t < off) s[t] += s[t + off];
    __syncthreads();
  }
  if (t == 0) bsum[blockIdx.x] = s[0];
}

__global__ void k_scan2(const int* __restrict__ bsum, int* __restrict__ boff, int nb) {
  __shared__ int s[256];
  int t = threadIdx.x;
  int v = (t < nb) ? bsum[t] : 0;
  s[t] = v; __syncthreads();
  for (int off = 1; off < 256; off <<= 1) {
    int tv = (t >= off) ? s[t - off] : 0;
    __syncthreads();
    s[t] += tv;
    __syncthreads();
  }
  if (t < nb) boff[t] = s[t] - v;
}

__global__ void k_scan3(const int* __restrict__ deg, const int* __restrict__ boff,
                        int* __restrict__ rowptr, int n, int Etot) {
  __shared__ int s[256];
  int t = threadIdx.x, i = blockIdx.x * 256 + t;
  int v = (i < n) ? deg[i] : 0;
  s[t] = v; __syncthreads();
  for (int off = 1; off < 256; off <<= 1) {
    int tv = (t >= off) ? s[t - off] : 0;
    __syncthreads();
    s[t] += tv;
    __syncthreads();
  }
  if (i < n) rowptr[i] = boff[blockIdx.x] + s[t] - v;
  if (i == 0) rowptr[n] = Etot;
}

__global__ void k_scatter(const void* __restrict__ ei, const int* __restrict__ rowptr,
                          int* __restrict__ cnt, int* __restrict__ esrc, int E,
                          const int* __restrict__ flags) {
  bool i64 = flags[1] != 0;
  int e = blockIdx.x * 256 + threadIdx.x;
  if (e < E) {
    int d = ldidx(ei, (size_t)E + e, i64);
    int s = ldidx(ei, (size_t)e, i64);
    int pos = rowptr[d] + atomicAdd(&cnt[d], 1);
    esrc[pos] = s;
  }
}

// ---------------- weight preconversion to bf16 ----------------
__global__ void k_wconv(const float* __restrict__ wa, const float* __restrict__ wb,
                        ushort* __restrict__ Wcat, ushort* __restrict__ Wbb) {
  int i = blockIdx.x * 256 + threadIdx.x;   // grid covers 32768
  if (i < 32768) {
    int c = i >> 7, k = i & 127;
    float v = (c < 128) ? wa[c * 256 + k] - wa[c * 256 + 128 + k]
                        : wa[(c - 128) * 256 + 128 + k];
    Wcat[i] = f2b(v);
  }
  if (i < 16384) Wbb[i] = f2b(wb[i]);
}

// ================= unified LDS-staged MFMA GEMM =================
// EPI 0 (WN=16): Y = X @ Wcat^T; cols 0-127 +bias -> A1 bf16; cols 128-255 -> A2 bf16
// EPI 1 (WN=8):  Y = l2norm(relu(X @ Wb^T + deg*bias)) -> bf16
// EPI 2 (WN=8):  Y = X @ Wb^T + deg*bias -> f32
// Block: 4 waves x 32 rows (dual 16-row A-tiles per wave) = 128 rows.
template <int EPI, typename TIN>
__global__ __launch_bounds__(256) void k_gemm(const TIN* __restrict__ X,
                                              const ushort* __restrict__ W,
                                              const float* __restrict__ bias,
                                              const int* __restrict__ deg,
                                              void* __restrict__ Y1,
                                              ushort* __restrict__ Y2, int nN) {
  constexpr int WN = (EPI == 0) ? 16 : 8;
  __shared__ ushort wlds[WN * 16 * WPAD];
  const int t = threadIdx.x;
  const int wave = t >> 6, lane = t & 63;
  const int ln = lane & 15, quad = lane >> 4;

  // ---- stage weights: [WN*16 rows][128 k] global -> LDS (padded rows) ----
  for (int i = t; i < WN * 256; i += 256) {   // uint4 chunks: row = i>>4, chunk = i&15
    int row = i >> 4, ch = i & 15;
    *(uint4*)&wlds[row * WPAD + ch * 8] = *(const uint4*)&W[row * CCH + ch * 8];
  }
  __syncthreads();

  const int rowb0 = blockIdx.x * 128 + wave * 32;   // tile0 rows
  const int rowb1 = rowb0 + 16;                     // tile1 rows
  const int ar0 = rowb0 + ln, ar1 = rowb1 + ln;

  // ---- A fragments (dual tile) ----
  ABu a0[4], a1[4];
#pragma unroll
  for (int kk = 0; kk < 4; ++kk) {
    if constexpr (sizeof(TIN) == 4) {
      auto ldc = [&](int r, ABu& d) {
        if (r < nN) {
          const float* xp = (const float*)X + (size_t)r * CCH + kk * 32 + quad * 8;
          float4 f0 = *(const float4*)xp;
          float4 f1 = *(const float4*)(xp + 4);
          d.u[0] = f2b(f0.x); d.u[1] = f2b(f0.y); d.u[2] = f2b(f0.z); d.u[3] = f2b(f0.w);
          d.u[4] = f2b(f1.x); d.u[5] = f2b(f1.y); d.u[6] = f2b(f1.z); d.u[7] = f2b(f1.w);
        } else d.q = make_uint4(0, 0, 0, 0);
      };
      ldc(ar0, a0[kk]); ldc(ar1, a1[kk]);
    } else {
      a0[kk].q = (ar0 < nN) ? *(const uint4*)((const ushort*)X + (size_t)ar0 * CCH + kk * 32 + quad * 8)
                            : make_uint4(0, 0, 0, 0);
      a1[kk].q = (ar1 < nN) ? *(const uint4*)((const ushort*)X + (size_t)ar1 * CCH + kk * 32 + quad * 8)
                            : make_uint4(0, 0, 0, 0);
    }
  }

  f32x4 acc0[WN], acc1[WN];
#pragma unroll
  for (int s = 0; s < WN; ++s) {
    acc0[s] = (f32x4){0.f, 0.f, 0.f, 0.f};
    acc1[s] = (f32x4){0.f, 0.f, 0.f, 0.f};
  }

#pragma unroll
  for (int s = 0; s < WN; ++s) {
#pragma unroll
    for (int kk = 0; kk < 4; ++kk) {
      ABu b;
      b.q = *(const uint4*)&wlds[(s * 16 + ln) * WPAD + kk * 32 + quad * 8];
      acc0[s] = __builtin_amdgcn_mfma_f32_16x16x32_bf16(a0[kk].v, b.v, acc0[s], 0, 0, 0);
      acc1[s] = __builtin_amdgcn_mfma_f32_16x16x32_bf16(a1[kk].v, b.v, acc1[s], 0, 0, 0);
    }
  }

  // ---- epilogues (C/D: row = tilebase + quad*4 + r, col = s*16 + ln) ----
  if constexpr (EPI == 0) {
    ushort* A1 = (ushort*)Y1;
#pragma unroll
    for (int s = 0; s < 16; ++s) {
      int col = s * 16 + ln;
      float bv = (s < 8) ? bias[col] : 0.f;
#pragma unroll
      for (int r = 0; r < 4; ++r) {
        int row0 = rowb0 + quad * 4 + r, row1 = rowb1 + quad * 4 + r;
        if (row0 < nN) {
          if (s < 8) A1[(size_t)row0 * CCH + col] = f2b(acc0[s][r] + bv);
          else       Y2[(size_t)row0 * CCH + (col - 128)] = f2b(acc0[s][r]);
        }
        if (row1 < nN) {
          if (s < 8) A1[(size_t)row1 * CCH + col] = f2b(acc1[s][r] + bv);
          else       Y2[(size_t)row1 * CCH + (col - 128)] = f2b(acc1[s][r]);
        }
      }
    }
  } else if constexpr (EPI == 1) {
    ushort* H = (ushort*)Y1;
    float biasv[8];
#pragma unroll
    for (int s = 0; s < 8; ++s) biasv[s] = bias[s * 16 + ln];
    auto epi = [&](f32x4* acc, int rowb) {
#pragma unroll
      for (int r = 0; r < 4; ++r) {
        int row = rowb + quad * 4 + r;
        float dn = (row < nN) ? (float)deg[row] : 0.f;
        float vals[8];
        float ss = 0.f;
#pragma unroll
        for (int s = 0; s < 8; ++s) {
          float v = fmaxf(acc[s][r] + dn * biasv[s], 0.f);
          vals[s] = v;
          ss += v * v;
        }
        ss += __shfl_xor(ss, 1, 64);
        ss += __shfl_xor(ss, 2, 64);
        ss += __shfl_xor(ss, 4, 64);
        ss += __shfl_xor(ss, 8, 64);
        float inv = 1.0f / fmaxf(sqrtf(ss), 1e-12f);
        if (row < nN) {
#pragma unroll
          for (int s = 0; s < 8; ++s)
            H[(size_t)row * CCH + s * 16 + ln] = f2b(vals[s] * inv);
        }
      }
    };
    epi(acc0, rowb0); epi(acc1, rowb1);
  } else {
    float* OUT = (float*)Y1;
    float biasv[8];
#pragma unroll
    for (int s = 0; s < 8; ++s) biasv[s] = bias[s * 16 + ln];
    auto epi = [&](f32x4* acc, int rowb) {
#pragma unroll
      for (int r = 0; r < 4; ++r) {
        int row = rowb + quad * 4 + r;
        if (row >= nN) continue;
        float dn = (float)deg[row];
#pragma unroll
        for (int s = 0; s < 8; ++s)
          OUT[(size_t)row * CCH + s * 16 + ln] = acc[s][r] + dn * biasv[s];
      }
    };
    epi(acc0, rowb0); epi(acc1, rowb1);
  }
}

// ---------------- edge aggregation v3 (quarter-wave per edge, 8 ch/lane) ----------------
// M(bf16) = scale * sum_e relu(A1 + A2[src]) + deg*shift;  A1 bf16 now
__global__ __launch_bounds__(256) void k_aggr(const ushort* __restrict__ A1,
                                              const ushort* __restrict__ A2,
                                              const int* __restrict__ rowptr,
                                              const int* __restrict__ esrc,
                                              const float* __restrict__ g,
                                              const float* __restrict__ be,
                                              const float* __restrict__ rm,
                                              const float* __restrict__ rv,
                                              ushort* __restrict__ M, int nNodes) {
  int node = blockIdx.x * 4 + (threadIdx.x >> 6);
  if (node >= nNodes) return;
  int lane = threadIdx.x & 63;
  int q = lane >> 4;            // edge slot 0..3
  int c = (lane & 15) * 8;      // 8 channels per lane

  uint4 aq = *(const uint4*)&A1[(size_t)node * CCH + c];
  float a[8] = {b2f((ushort)aq.x), b2f((ushort)(aq.x >> 16)),
                b2f((ushort)aq.y), b2f((ushort)(aq.y >> 16)),
                b2f((ushort)aq.z), b2f((ushort)(aq.z >> 16)),
                b2f((ushort)aq.w), b2f((ushort)(aq.w >> 16))};
  int r0 = rowptr[node], r1 = rowptr[node + 1];
  float s[8] = {0.f, 0.f, 0.f, 0.f, 0.f, 0.f, 0.f, 0.f};

  int e = r0 + q;
  for (; e + 4 < r1; e += 8) {           // 2 edges per quarter-wave iter
    int sA = esrc[e], sB = esrc[e + 4];
    uint4 wA = *(const uint4*)&A2[(size_t)sA * CCH + c];
    uint4 wB = *(const uint4*)&A2[(size_t)sB * CCH + c];
    const unsigned* pA = (const unsigned*)&wA;
    const unsigned* pB = (const unsigned*)&wB;
#pragma unroll
    for (int j = 0; j < 4; ++j) {
      s[2*j]   += fmaxf(a[2*j]   + b2f((ushort)pA[j]), 0.f);
      s[2*j+1] += fmaxf(a[2*j+1] + b2f((ushort)(pA[j] >> 16)), 0.f);
      s[2*j]   += fmaxf(a[2*j]   + b2f((ushort)pB[j]), 0.f);
      s[2*j+1] += fmaxf(a[2*j+1] + b2f((ushort)(pB[j] >> 16)), 0.f);
    }
  }
  for (; e < r1; e += 4) {
    int sA = esrc[e];
    uint4 wA = *(const uint4*)&A2[(size_t)sA * CCH + c];
    const unsigned* pA = (const unsigned*)&wA;
#pragma unroll
    for (int j = 0; j < 4; ++j) {
      s[2*j]   += fmaxf(a[2*j]   + b2f((ushort)pA[j]), 0.f);
      s[2*j+1] += fmaxf(a[2*j+1] + b2f((ushort)(pA[j] >> 16)), 0.f);
    }
  }
#pragma unroll
  for (int j = 0; j < 8; ++j) {
    s[j] += __shfl_xor(s[j], 16, 64);
    s[j] += __shfl_xor(s[j], 32, 64);
  }

  if (q == 0) {
    float dn = (float)(r1 - r0);
    unsigned p[4];
#pragma unroll
    for (int j = 0; j < 4; ++j) {
      float sc0 = g[c + 2*j]     * rsqrtf(rv[c + 2*j]     + 1e-5f);
      float sc1 = g[c + 2*j + 1] * rsqrtf(rv[c + 2*j + 1] + 1e-5f);
      float o0 = sc0 * s[2*j]     + dn * (be[c + 2*j]     - rm[c + 2*j]     * sc0);
      float o1 = sc1 * s[2*j + 1] + dn * (be[c + 2*j + 1] - rm[c + 2*j + 1] * sc1);
      p[j] = (unsigned)f2b(o0) | ((unsigned)f2b(o1) << 16);
    }
    *(uint4*)&M[(size_t)node * CCH + c] = make_uint4(p[0], p[1], p[2], p[3]);
  }
}

// ---------------- launch ----------------
extern "C" void kernel_launch(void* const* d_in, const int* in_sizes, int n_in,
                              void* d_out, int out_size, void* d_ws, size_t ws_size,
                              hipStream_t stream) {
  const float* x   = (const float*)d_in[0];
  const void*  ei  = d_in[1];
  const float* w1a = (const float*)d_in[2];
  const float* b1a = (const float*)d_in[3];
  const float* g1  = (const float*)d_in[4];
  const float* be1 = (const float*)d_in[5];
  const float* rm1 = (const float*)d_in[6];
  const float* rv1 = (const float*)d_in[7];
  const float* w1b = (const float*)d_in[8];
  const float* b1b = (const float*)d_in[9];
  const float* w2a = (const float*)d_in[10];
  const float* b2a = (const float*)d_in[11];
  const float* g2  = (const float*)d_in[12];
  const float* be2 = (const float*)d_in[13];
  const float* rm2 = (const float*)d_in[14];
  const float* rv2 = (const float*)d_in[15];
  const float* w2b = (const float*)d_in[16];
  const float* b2b = (const float*)d_in[17];

  const int N = in_sizes[0] / CCH;   // 50000
  const int E = in_sizes[1] / 2;     // 600000
  const size_t NC = (size_t)N * CCH;

  int* flags  = (int*)d_ws;              // 4
  int* deg    = flags + 4;               // N
  int* cnt    = deg + N;                 // N
  int* rowptr = cnt + N;                 // N+1
  int* bsum   = rowptr + N + 1;          // 256
  int* boff   = bsum + 256;              // 256
  int* esrc   = boff + 256;              // E
  uintptr_t pw = ((uintptr_t)(esrc + E) + 63) & ~(uintptr_t)63;
  ushort* Wcat1 = (ushort*)pw;           // 256*128
  ushort* Wcat2 = Wcat1 + 32768;         // 256*128
  ushort* Wb1   = Wcat2 + 32768;         // 128*128
  ushort* Wb2   = Wb1 + 16384;           // 128*128
  uintptr_t pb = ((uintptr_t)(Wb2 + 16384) + 63) & ~(uintptr_t)63;
  ushort* B0 = (ushort*)pb;              // NC bf16 (A1)
  ushort* B1 = B0 + NC;                  // NC bf16 (A2)
  ushort* MB = B1 + NC;                  // NC bf16 (M)
  ushort* HB = MB + NC;                  // NC bf16 (H)
  // total ≈ 3.4 MB + 0.2 MB + 4 × 12.8 MB ≈ 55 MB

  const int gE = (E + 255) / 256;
  const int gS = (N + 255) / 256;
  const int gG = (N + 127) / 128;   // 391
  const int gA = (N + 3) / 4;       // 12500

  k_detect<<<1, 256, 0, stream>>>((const unsigned int*)ei, flags);
  hipMemsetAsync(deg, 0, sizeof(int) * 2 * (size_t)N, stream);
  k_wconv<<<128, 256, 0, stream>>>(w1a, w1b, Wcat1, Wb1);
  k_wconv<<<128, 256, 0, stream>>>(w2a, w2b, Wcat2, Wb2);
  k_hist<<<gE, 256, 0, stream>>>(ei, deg, E, flags);
  k_scan1<<<gS, 256, 0, stream>>>(deg, bsum, N);
  k_scan2<<<1, 256, 0, stream>>>(bsum, boff, gS);
  k_scan3<<<gS, 256, 0, stream>>>(deg, boff, rowptr, N, E);
  k_scatter<<<gE, 256, 0, stream>>>(ei, rowptr, cnt, esrc, E, flags);

  // ---- layer 1 ----
  k_gemm<0, float><<<gG, 256, 0, stream>>>(x, Wcat1, b1a, nullptr, B0, B1, N);       // A1,A2
  k_aggr<<<gA, 256, 0, stream>>>(B0, B1, rowptr, esrc, g1, be1, rm1, rv1, MB, N);    // M1
  k_gemm<1, ushort><<<gG, 256, 0, stream>>>(MB, Wb1, b1b, deg, HB, nullptr, N);      // H
  // ---- layer 2 ----
  k_gemm<0, ushort><<<gG, 256, 0, stream>>>(HB, Wcat2, b2a, nullptr, B0, B1, N);     // A1,A2
  k_aggr<<<gA, 256, 0, stream>>>(B0, B1, rowptr, esrc, g2, be2, rm2, rv2, MB, N);    // M2
  k_gemm<2, ushort><<<gG, 256, 0, stream>>>(MB, Wb2, b2b, deg, d_out, nullptr, N);   // out
}

// Round 7
// 300.806 us; speedup vs baseline: 3.1970x; 1.0418x over previous
//
#include <hip/hip_runtime.h>

#define CCH 128
#define WPAD 136   // LDS row stride in ushorts (272B): bank-spread, 16B aligned
typedef unsigned short ushort;
typedef __attribute__((ext_vector_type(8))) short bf16x8_t;
typedef __attribute__((ext_vector_type(4))) float f32x4;

union ABu { bf16x8_t v; ushort u[8]; uint4 q; };

__device__ __forceinline__ ushort f2b(float f) {   // fp32 -> bf16 RNE
  union { float f; unsigned u; } v{f};
  unsigned r = v.u + 0x7fffu + ((v.u >> 16) & 1u);
  return (ushort)(r >> 16);
}
__device__ __forceinline__ float b2f(ushort s) {
  union { unsigned u; float f; } v{(unsigned)s << 16};
  return v.f;
}

__device__ __forceinline__ int ldidx(const void* ei, size_t i, bool i64) {
  return i64 ? (int)((const long long*)ei)[i] : ((const int*)ei)[i];
}

// ---------------- init: zero deg/cnt + dtype detect + weight conversion ----------------
__global__ void k_init(const unsigned int* __restrict__ eiw, int* __restrict__ flags,
                       int* __restrict__ degcnt, int n2,
                       const float* __restrict__ w1a, const float* __restrict__ w1b,
                       const float* __restrict__ w2a, const float* __restrict__ w2b,
                       ushort* __restrict__ Wcat1, ushort* __restrict__ Wb1,
                       ushort* __restrict__ Wcat2, ushort* __restrict__ Wb2) {
  int b = blockIdx.x, t = threadIdx.x;
  int gid = b * 256 + t;
  if (gid < n2) degcnt[gid] = 0;

  if (b < 128) {                       // layer-1 weights
    int i = gid;                       // 0..32767
    int c = i >> 7, k = i & 127;
    float v = (c < 128) ? w1a[c * 256 + k] - w1a[c * 256 + 128 + k]
                        : w1a[(c - 128) * 256 + 128 + k];
    Wcat1[i] = f2b(v);
    if (i < 16384) Wb1[i] = f2b(w1b[i]);
  } else if (b < 256) {                // layer-2 weights
    int i = gid - 32768;
    int c = i >> 7, k = i & 127;
    float v = (c < 128) ? w2a[c * 256 + k] - w2a[c * 256 + 128 + k]
                        : w2a[(c - 128) * 256 + 128 + k];
    Wcat2[i] = f2b(v);
    if (i < 16384) Wb2[i] = f2b(w2b[i]);
  } else if (b == 256) {               // edge-index width detect
    __shared__ int cz;
    if (t == 0) cz = 0;
    __syncthreads();
    if (eiw[2 * t + 1] != 0u) atomicAdd(&cz, 1);
    __syncthreads();
    if (t == 0) flags[1] = (cz == 0) ? 1 : 0;
  }
}

// ---------------- CSR build ----------------
__global__ void k_hist(const void* __restrict__ ei, int* __restrict__ deg, int E,
                       const int* __restrict__ flags) {
  bool i64 = flags[1] != 0;
  int e = blockIdx.x * 256 + threadIdx.x;
  if (e < E) atomicAdd(&deg[ldidx(ei, (size_t)E + e, i64)], 1);
}

__global__ void k_scan1(const int* __restrict__ deg, int* __restrict__ bsum, int n) {
  __shared__ int s[256];
  int t = threadIdx.x, i = blockIdx.x * 256 + t;
  s[t] = (i < n) ? deg[i] : 0;
  __syncthreads();
  for (int off = 128; off > 0; off >>= 1) {
    if (t < off) s[t] += s[t + off];
    __syncthreads();
  }
  if (t == 0) bsum[blockIdx.x] = s[0];
}

__global__ void k_scan2(const int* __restrict__ bsum, int* __restrict__ boff, int nb) {
  __shared__ int s[256];
  int t = threadIdx.x;
  int v = (t < nb) ? bsum[t] : 0;
  s[t] = v; __syncthreads();
  for (int off = 1; off < 256; off <<= 1) {
    int tv = (t >= off) ? s[t - off] : 0;
    __syncthreads();
    s[t] += tv;
    __syncthreads();
  }
  if (t < nb) boff[t] = s[t] - v;
}

__global__ void k_scan3(const int* __restrict__ deg, const int* __restrict__ boff,
                        int* __restrict__ rowptr, int n, int Etot) {
  __shared__ int s[256];
  int t = threadIdx.x, i = blockIdx.x * 256 + t;
  int v = (i < n) ? deg[i] : 0;
  s[t] = v; __syncthreads();
  for (int off = 1; off < 256; off <<= 1) {
    int tv = (t >= off) ? s[t - off] : 0;
    __syncthreads();
    s[t] += tv;
    __syncthreads();
  }
  if (i < n) rowptr[i] = boff[blockIdx.x] + s[t] - v;
  if (i == 0) rowptr[n] = Etot;
}

__global__ void k_scatter(const void* __restrict__ ei, const int* __restrict__ rowptr,
                          int* __restrict__ cnt, int* __restrict__ esrc, int E,
                          const int* __restrict__ flags) {
  bool i64 = flags[1] != 0;
  int e = blockIdx.x * 256 + threadIdx.x;
  if (e < E) {
    int d = ldidx(ei, (size_t)E + e, i64);
    int s = ldidx(ei, (size_t)e, i64);
    int pos = rowptr[d] + atomicAdd(&cnt[d], 1);
    esrc[pos] = s;
  }
}

// ================= LDS-staged MFMA GEMM, 64 rows/block, 128 cols =================
// EPI 0: gridDim.y=2. y=0: A1 = X@Wcat[0:128]^T + bias (bf16); y=1: A2 = X@Wcat[128:256]^T (bf16)
// EPI 1: H = l2norm(relu(X@Wb^T + deg*bias)) (bf16)
// EPI 2: OUT = X@Wb^T + deg*bias (f32)
// Block: 4 waves x 16 rows. LDS 34 KB -> 4 blocks/CU.
template <int EPI, typename TIN>
__global__ __launch_bounds__(256) void k_gemm(const TIN* __restrict__ X,
                                              const ushort* __restrict__ W,
                                              const float* __restrict__ bias,
                                              const int* __restrict__ deg,
                                              void* __restrict__ Y1,
                                              ushort* __restrict__ Y2, int nN) {
  __shared__ ushort wlds[128 * WPAD];
  const int t = threadIdx.x;
  const int wave = t >> 6, lane = t & 63;
  const int ln = lane & 15, quad = lane >> 4;
  const int half = (EPI == 0) ? blockIdx.y : 0;

  // ---- stage 128 weight rows (this col-half) into LDS ----
  const ushort* Wp = W + (size_t)half * 128 * CCH;
  for (int i = t; i < 128 * 16; i += 256) {   // uint4 chunks
    int row = i >> 4, ch = i & 15;
    *(uint4*)&wlds[row * WPAD + ch * 8] = *(const uint4*)&Wp[row * CCH + ch * 8];
  }
  __syncthreads();

  const int rowb = blockIdx.x * 64 + wave * 16;
  const int arow = rowb + ln;

  // ---- A fragments (one 16-row tile per wave, K=128) ----
  ABu a[4];
#pragma unroll
  for (int kk = 0; kk < 4; ++kk) {
    if constexpr (sizeof(TIN) == 4) {
      if (arow < nN) {
        const float* xp = (const float*)X + (size_t)arow * CCH + kk * 32 + quad * 8;
        float4 f0 = *(const float4*)xp;
        float4 f1 = *(const float4*)(xp + 4);
        a[kk].u[0] = f2b(f0.x); a[kk].u[1] = f2b(f0.y); a[kk].u[2] = f2b(f0.z); a[kk].u[3] = f2b(f0.w);
        a[kk].u[4] = f2b(f1.x); a[kk].u[5] = f2b(f1.y); a[kk].u[6] = f2b(f1.z); a[kk].u[7] = f2b(f1.w);
      } else a[kk].q = make_uint4(0, 0, 0, 0);
    } else {
      a[kk].q = (arow < nN) ? *(const uint4*)((const ushort*)X + (size_t)arow * CCH + kk * 32 + quad * 8)
                            : make_uint4(0, 0, 0, 0);
    }
  }

  f32x4 acc[8];
#pragma unroll
  for (int s = 0; s < 8; ++s) acc[s] = (f32x4){0.f, 0.f, 0.f, 0.f};

#pragma unroll
  for (int s = 0; s < 8; ++s) {
#pragma unroll
    for (int kk = 0; kk < 4; ++kk) {
      ABu b;
      b.q = *(const uint4*)&wlds[(s * 16 + ln) * WPAD + kk * 32 + quad * 8];
      acc[s] = __builtin_amdgcn_mfma_f32_16x16x32_bf16(a[kk].v, b.v, acc[s], 0, 0, 0);
    }
  }

  // ---- epilogue (C/D: local row = quad*4+r, col = s*16+ln) ----
  if constexpr (EPI == 0) {
    ushort* dst = half ? Y2 : (ushort*)Y1;
#pragma unroll
    for (int s = 0; s < 8; ++s) {
      int col = s * 16 + ln;
      float bv = half ? 0.f : bias[col];
#pragma unroll
      for (int r = 0; r < 4; ++r) {
        int row = rowb + quad * 4 + r;
        if (row < nN) dst[(size_t)row * CCH + col] = f2b(acc[s][r] + bv);
      }
    }
  } else if constexpr (EPI == 1) {
    ushort* H = (ushort*)Y1;
    float biasv[8];
#pragma unroll
    for (int s = 0; s < 8; ++s) biasv[s] = bias[s * 16 + ln];
#pragma unroll
    for (int r = 0; r < 4; ++r) {
      int row = rowb + quad * 4 + r;
      float dn = (row < nN) ? (float)deg[row] : 0.f;
      float vals[8];
      float ss = 0.f;
#pragma unroll
      for (int s = 0; s < 8; ++s) {
        float v = fmaxf(acc[s][r] + dn * biasv[s], 0.f);
        vals[s] = v;
        ss += v * v;
      }
      ss += __shfl_xor(ss, 1, 64);
      ss += __shfl_xor(ss, 2, 64);
      ss += __shfl_xor(ss, 4, 64);
      ss += __shfl_xor(ss, 8, 64);
      float inv = 1.0f / fmaxf(sqrtf(ss), 1e-12f);
      if (row < nN) {
#pragma unroll
        for (int s = 0; s < 8; ++s)
          H[(size_t)row * CCH + s * 16 + ln] = f2b(vals[s] * inv);
      }
    }
  } else {
    float* OUT = (float*)Y1;
    float biasv[8];
#pragma unroll
    for (int s = 0; s < 8; ++s) biasv[s] = bias[s * 16 + ln];
#pragma unroll
    for (int r = 0; r < 4; ++r) {
      int row = rowb + quad * 4 + r;
      if (row >= nN) continue;
      float dn = (float)deg[row];
#pragma unroll
      for (int s = 0; s < 8; ++s)
        OUT[(size_t)row * CCH + s * 16 + ln] = acc[s][r] + dn * biasv[s];
    }
  }
}

// ---------------- edge aggregation (quarter-wave per edge, 8 ch/lane) ----------------
__global__ __launch_bounds__(256) void k_aggr(const ushort* __restrict__ A1,
                                              const ushort* __restrict__ A2,
                                              const int* __restrict__ rowptr,
                                              const int* __restrict__ esrc,
                                              const float* __restrict__ g,
                                              const float* __restrict__ be,
                                              const float* __restrict__ rm,
                                              const float* __restrict__ rv,
                                              ushort* __restrict__ M, int nNodes) {
  int node = blockIdx.x * 4 + (threadIdx.x >> 6);
  if (node >= nNodes) return;
  int lane = threadIdx.x & 63;
  int q = lane >> 4;            // edge slot 0..3
  int c = (lane & 15) * 8;      // 8 channels per lane

  uint4 aq = *(const uint4*)&A1[(size_t)node * CCH + c];
  float a[8] = {b2f((ushort)aq.x), b2f((ushort)(aq.x >> 16)),
                b2f((ushort)aq.y), b2f((ushort)(aq.y >> 16)),
                b2f((ushort)aq.z), b2f((ushort)(aq.z >> 16)),
                b2f((ushort)aq.w), b2f((ushort)(aq.w >> 16))};
  int r0 = rowptr[node], r1 = rowptr[node + 1];
  float s[8] = {0.f, 0.f, 0.f, 0.f, 0.f, 0.f, 0.f, 0.f};

  int e = r0 + q;
  for (; e + 4 < r1; e += 8) {
    int sA = esrc[e], sB = esrc[e + 4];
    uint4 wA = *(const uint4*)&A2[(size_t)sA * CCH + c];
    uint4 wB = *(const uint4*)&A2[(size_t)sB * CCH + c];
    const unsigned* pA = (const unsigned*)&wA;
    const unsigned* pB = (const unsigned*)&wB;
#pragma unroll
    for (int j = 0; j < 4; ++j) {
      s[2*j]   += fmaxf(a[2*j]   + b2f((ushort)pA[j]), 0.f);
      s[2*j+1] += fmaxf(a[2*j+1] + b2f((ushort)(pA[j] >> 16)), 0.f);
      s[2*j]   += fmaxf(a[2*j]   + b2f((ushort)pB[j]), 0.f);
      s[2*j+1] += fmaxf(a[2*j+1] + b2f((ushort)(pB[j] >> 16)), 0.f);
    }
  }
  for (; e < r1; e += 4) {
    int sA = esrc[e];
    uint4 wA = *(const uint4*)&A2[(size_t)sA * CCH + c];
    const unsigned* pA = (const unsigned*)&wA;
#pragma unroll
    for (int j = 0; j < 4; ++j) {
      s[2*j]   += fmaxf(a[2*j]   + b2f((ushort)pA[j]), 0.f);
      s[2*j+1] += fmaxf(a[2*j+1] + b2f((ushort)(pA[j] >> 16)), 0.f);
    }
  }
#pragma unroll
  for (int j = 0; j < 8; ++j) {
    s[j] += __shfl_xor(s[j], 16, 64);
    s[j] += __shfl_xor(s[j], 32, 64);
  }

  if (q == 0) {
    float dn = (float)(r1 - r0);
    unsigned p[4];
#pragma unroll
    for (int j = 0; j < 4; ++j) {
      float sc0 = g[c + 2*j]     * rsqrtf(rv[c + 2*j]     + 1e-5f);
      float sc1 = g[c + 2*j + 1] * rsqrtf(rv[c + 2*j + 1] + 1e-5f);
      float o0 = sc0 * s[2*j]     + dn * (be[c + 2*j]     - rm[c + 2*j]     * sc0);
      float o1 = sc1 * s[2*j + 1] + dn * (be[c + 2*j + 1] - rm[c + 2*j + 1] * sc1);
      p[j] = (unsigned)f2b(o0) | ((unsigned)f2b(o1) << 16);
    }
    *(uint4*)&M[(size_t)node * CCH + c] = make_uint4(p[0], p[1], p[2], p[3]);
  }
}

// ---------------- launch ----------------
extern "C" void kernel_launch(void* const* d_in, const int* in_sizes, int n_in,
                              void* d_out, int out_size, void* d_ws, size_t ws_size,
                              hipStream_t stream) {
  const float* x   = (const float*)d_in[0];
  const void*  ei  = d_in[1];
  const float* w1a = (const float*)d_in[2];
  const float* b1a = (const float*)d_in[3];
  const float* g1  = (const float*)d_in[4];
  const float* be1 = (const float*)d_in[5];
  const float* rm1 = (const float*)d_in[6];
  const float* rv1 = (const float*)d_in[7];
  const float* w1b = (const float*)d_in[8];
  const float* b1b = (const float*)d_in[9];
  const float* w2a = (const float*)d_in[10];
  const float* b2a = (const float*)d_in[11];
  const float* g2  = (const float*)d_in[12];
  const float* be2 = (const float*)d_in[13];
  const float* rm2 = (const float*)d_in[14];
  const float* rv2 = (const float*)d_in[15];
  const float* w2b = (const float*)d_in[16];
  const float* b2b = (const float*)d_in[17];

  const int N = in_sizes[0] / CCH;   // 50000
  const int E = in_sizes[1] / 2;     // 600000
  const size_t NC = (size_t)N * CCH;

  int* flags  = (int*)d_ws;              // 4
  int* deg    = flags + 4;               // N
  int* cnt    = deg + N;                 // N   (contiguous after deg)
  int* rowptr = cnt + N;                 // N+1
  int* bsum   = rowptr + N + 1;          // 256
  int* boff   = bsum + 256;              // 256
  int* esrc   = boff + 256;              // E
  uintptr_t pw = ((uintptr_t)(esrc + E) + 63) & ~(uintptr_t)63;
  ushort* Wcat1 = (ushort*)pw;           // 256*128
  ushort* Wcat2 = Wcat1 + 32768;         // 256*128
  ushort* Wb1   = Wcat2 + 32768;         // 128*128
  ushort* Wb2   = Wb1 + 16384;           // 128*128
  uintptr_t pb = ((uintptr_t)(Wb2 + 16384) + 63) & ~(uintptr_t)63;
  ushort* B0 = (ushort*)pb;              // NC bf16 (A1)
  ushort* B1 = B0 + NC;                  // NC bf16 (A2)
  ushort* MB = B1 + NC;                  // NC bf16 (M)
  ushort* HB = MB + NC;                  // NC bf16 (H)

  const int gE = (E + 255) / 256;
  const int gS = (N + 255) / 256;
  const int gG = (N + 63) / 64;          // 782
  const int gA = (N + 3) / 4;            // 12500
  int gInit = (2 * N + 255) / 256;
  if (gInit < 257) gInit = 257;

  k_init<<<gInit, 256, 0, stream>>>((const unsigned int*)ei, flags, deg, 2 * N,
                                    w1a, w1b, w2a, w2b, Wcat1, Wb1, Wcat2, Wb2);
  k_hist<<<gE, 256, 0, stream>>>(ei, deg, E, flags);
  k_scan1<<<gS, 256, 0, stream>>>(deg, bsum, N);
  k_scan2<<<1, 256, 0, stream>>>(bsum, boff, gS);
  k_scan3<<<gS, 256, 0, stream>>>(deg, boff, rowptr, N, E);
  k_scatter<<<gE, 256, 0, stream>>>(ei, rowptr, cnt, esrc, E, flags);

  // ---- layer 1 ----
  k_gemm<0, float><<<dim3(gG, 2), 256, 0, stream>>>(x, Wcat1, b1a, deg, B0, B1, N);
  k_aggr<<<gA, 256, 0, stream>>>(B0, B1, rowptr, esrc, g1, be1, rm1, rv1, MB, N);
  k_gemm<1, ushort><<<gG, 256, 0, stream>>>(MB, Wb1, b1b, deg, HB, nullptr, N);
  // ---- layer 2 ----
  k_gemm<0, ushort><<<dim3(gG, 2), 256, 0, stream>>>(HB, Wcat2, b2a, deg, B0, B1, N);
  k_aggr<<<gA, 256, 0, stream>>>(B0, B1, rowptr, esrc, g2, be2, rm2, rv2, MB, N);
  k_gemm<2, ushort><<<gG, 256, 0, stream>>>(MB, Wb2, b2b, deg, d_out, nullptr, N);
}

// Round 8
// 299.881 us; speedup vs baseline: 3.2069x; 1.0031x over previous
//
#include <hip/hip_runtime.h>

#define CCH 128
#define WPAD 136   // LDS row stride in ushorts (272B): 2-way-conflict-free for b128 reads
typedef unsigned short ushort;
typedef __attribute__((ext_vector_type(8))) short bf16x8_t;
typedef __attribute__((ext_vector_type(4))) float f32x4;

union ABu { bf16x8_t v; ushort u[8]; uint4 q; };

__device__ __forceinline__ ushort f2b(float f) {   // fp32 -> bf16 RNE
  union { float f; unsigned u; } v{f};
  unsigned r = v.u + 0x7fffu + ((v.u >> 16) & 1u);
  return (ushort)(r >> 16);
}
__device__ __forceinline__ float b2f(ushort s) {
  union { unsigned u; float f; } v{(unsigned)s << 16};
  return v.f;
}

// ================= pre: weight conv + x->bf16 + histogram (dtype self-detect) =========
// blocks [0,256): weight conversion; [256, 256+xcb): x->bf16; rest: histogram.
__global__ __launch_bounds__(256) void k_pre(const float* __restrict__ x,
                                             ushort* __restrict__ XB, int nxc,
                                             const float* __restrict__ w1a,
                                             const float* __restrict__ w1b,
                                             const float* __restrict__ w2a,
                                             const float* __restrict__ w2b,
                                             ushort* __restrict__ Wcat1, ushort* __restrict__ Wb1,
                                             ushort* __restrict__ Wcat2, ushort* __restrict__ Wb2,
                                             const void* __restrict__ ei, int* __restrict__ deg,
                                             int E, int xcb) {
  const int b = blockIdx.x, t = threadIdx.x;
  if (b < 128) {                       // layer-1 weights
    int i = b * 256 + t;
    int c = i >> 7, k = i & 127;
    float v = (c < 128) ? w1a[c * 256 + k] - w1a[c * 256 + 128 + k]
                        : w1a[(c - 128) * 256 + 128 + k];
    Wcat1[i] = f2b(v);
    if (i < 16384) Wb1[i] = f2b(w1b[i]);
  } else if (b < 256) {                // layer-2 weights
    int i = (b - 128) * 256 + t;
    int c = i >> 7, k = i & 127;
    float v = (c < 128) ? w2a[c * 256 + k] - w2a[c * 256 + 128 + k]
                        : w2a[(c - 128) * 256 + 128 + k];
    Wcat2[i] = f2b(v);
    if (i < 16384) Wb2[i] = f2b(w2b[i]);
  } else if (b < 256 + xcb) {          // x -> bf16 (8 floats / thread)
    size_t i = (size_t)(b - 256) * 256 + t;
    if (i < (size_t)nxc) {
      const float* xp = x + i * 8;
      float4 f0 = *(const float4*)xp;
      float4 f1 = *(const float4*)(xp + 4);
      ushort o[8] = {f2b(f0.x), f2b(f0.y), f2b(f0.z), f2b(f0.w),
                     f2b(f1.x), f2b(f1.y), f2b(f1.z), f2b(f1.w)};
      *(uint4*)&XB[i * 8] = *(const uint4*)o;
    }
  } else {                             // histogram with per-block dtype detect
    __shared__ int nz;
    if (t == 0) nz = 0;
    __syncthreads();
    int e = (b - 256 - xcb) * 256 + t;
    unsigned hi = (e < E) ? ((const unsigned*)ei)[2 * (size_t)e + 1] : 0u;  // in-bounds both ways
    if (hi) atomicAdd(&nz, 1);
    __syncthreads();
    bool i64 = (nz == 0);
    if (e < E) {
      int d = i64 ? (int)((const long long*)ei)[(size_t)E + e]
                  : ((const int*)ei)[(size_t)E + e];
      atomicAdd(&deg[d], 1);
    }
  }
}

// ================= rowptr: fused scan2+scan3 =================
__global__ __launch_bounds__(256) void k_rowptr(const int* __restrict__ deg,
                                                const int* __restrict__ bsum,
                                                int* __restrict__ rowptr,
                                                int n, int nb, int Etot) {
  __shared__ int s[256];
  const int t = threadIdx.x, b = blockIdx.x;
  // phase A: offset = sum of bsum[0..b)
  s[t] = (t < nb && t < b) ? bsum[t] : 0;
  __syncthreads();
  for (int off = 128; off > 0; off >>= 1) {
    if (t < off) s[t] += s[t + off];
    __syncthreads();
  }
  int boffset = s[0];
  __syncthreads();
  // phase B: local inclusive scan
  int i = b * 256 + t;
  int v = (i < n) ? deg[i] : 0;
  s[t] = v; __syncthreads();
  for (int off = 1; off < 256; off <<= 1) {
    int tv = (t >= off) ? s[t - off] : 0;
    __syncthreads();
    s[t] += tv;
    __syncthreads();
  }
  if (i < n) rowptr[i] = boffset + s[t] - v;
  if (b == gridDim.x - 1 && t == 0) rowptr[n] = Etot;
}

// ================= scatter (dtype self-detect) =================
__global__ __launch_bounds__(256) void k_scatter(const void* __restrict__ ei,
                                                 const int* __restrict__ rowptr,
                                                 int* __restrict__ cnt,
                                                 int* __restrict__ esrc, int E) {
  __shared__ int nz;
  const int t = threadIdx.x;
  if (t == 0) nz = 0;
  __syncthreads();
  int e = blockIdx.x * 256 + t;
  unsigned hi = (e < E) ? ((const unsigned*)ei)[2 * (size_t)e + 1] : 0u;
  if (hi) atomicAdd(&nz, 1);
  __syncthreads();
  bool i64 = (nz == 0);
  if (e < E) {
    int d, sv;
    if (i64) {
      sv = (int)((const long long*)ei)[(size_t)e];
      d  = (int)((const long long*)ei)[(size_t)E + e];
    } else {
      sv = ((const int*)ei)[(size_t)e];
      d  = ((const int*)ei)[(size_t)E + e];
    }
    int pos = rowptr[d] + atomicAdd(&cnt[d], 1);
    esrc[pos] = sv;
  }
}

// ================= GEMM body: dual 16-row tiles/wave, one 128-col half =================
// returns acc0/acc1 for rows rowb..rowb+31
__device__ __forceinline__ void gemm_core(const ushort* __restrict__ XB,
                                          const ushort* __restrict__ wlds,
                                          int rowb, int ln, int quad, int nN,
                                          f32x4 acc0[8], f32x4 acc1[8]) {
  const int ar0 = rowb + ln, ar1 = rowb + 16 + ln;
  ABu a0[4], a1[4];
#pragma unroll
  for (int kk = 0; kk < 4; ++kk) {
    a0[kk].q = (ar0 < nN) ? *(const uint4*)(XB + (size_t)ar0 * CCH + kk * 32 + quad * 8)
                          : make_uint4(0, 0, 0, 0);
    a1[kk].q = (ar1 < nN) ? *(const uint4*)(XB + (size_t)ar1 * CCH + kk * 32 + quad * 8)
                          : make_uint4(0, 0, 0, 0);
  }
#pragma unroll
  for (int s = 0; s < 8; ++s) {
    acc0[s] = (f32x4){0.f, 0.f, 0.f, 0.f};
    acc1[s] = (f32x4){0.f, 0.f, 0.f, 0.f};
  }
#pragma unroll
  for (int s = 0; s < 8; ++s) {
#pragma unroll
    for (int kk = 0; kk < 4; ++kk) {
      ABu b;
      b.q = *(const uint4*)&wlds[(s * 16 + ln) * WPAD + kk * 32 + quad * 8];
      acc0[s] = __builtin_amdgcn_mfma_f32_16x16x32_bf16(a0[kk].v, b.v, acc0[s], 0, 0, 0);
      acc1[s] = __builtin_amdgcn_mfma_f32_16x16x32_bf16(a1[kk].v, b.v, acc1[s], 0, 0, 0);
    }
  }
}

__device__ __forceinline__ void stage_w(const ushort* __restrict__ Wp,
                                        ushort* __restrict__ wlds, int t) {
  for (int i = t; i < 128 * 16; i += 256) {
    int row = i >> 4, ch = i & 15;
    *(uint4*)&wlds[row * WPAD + ch * 8] = *(const uint4*)&Wp[row * CCH + ch * 8];
  }
}

// EPI0 epilogue: bf16 store (+bias on half 0)
__device__ __forceinline__ void epi0(f32x4 acc[8], int rowb, int ln, int quad, int nN,
                                     const float* bias, int half, ushort* dst) {
#pragma unroll
  for (int s = 0; s < 8; ++s) {
    int col = s * 16 + ln;
    float bv = half ? 0.f : bias[col];
#pragma unroll
    for (int r = 0; r < 4; ++r) {
      int row = rowb + quad * 4 + r;
      if (row < nN) dst[(size_t)row * CCH + col] = f2b(acc[s][r] + bv);
    }
  }
}

// ---------------- mix1: layer-1 EPI0 GEMM (blocks [0,2*gH)) + scan1 (rest) ----------------
__global__ __launch_bounds__(256) void k_mix1(const ushort* __restrict__ XB,
                                              const ushort* __restrict__ Wcat,
                                              const float* __restrict__ bias,
                                              ushort* __restrict__ A1,
                                              ushort* __restrict__ A2, int nN,
                                              const int* __restrict__ deg,
                                              int* __restrict__ bsum, int gH, int n) {
  __shared__ ushort wlds[128 * WPAD];
  const int t = threadIdx.x;
  if ((int)blockIdx.x >= 2 * gH) {   // ---- scan1 ----
    int* s = (int*)wlds;
    int bb = blockIdx.x - 2 * gH;
    int i = bb * 256 + t;
    s[t] = (i < n) ? deg[i] : 0;
    __syncthreads();
    for (int off = 128; off > 0; off >>= 1) {
      if (t < off) s[t] += s[t + off];
      __syncthreads();
    }
    if (t == 0) bsum[bb] = s[0];
    return;
  }
  const int half = (int)blockIdx.x >= gH;
  const int bx = half ? blockIdx.x - gH : blockIdx.x;
  stage_w(Wcat + (size_t)half * 128 * CCH, wlds, t);
  __syncthreads();
  const int wave = t >> 6, lane = t & 63;
  const int ln = lane & 15, quad = lane >> 4;
  const int rowb = bx * 128 + wave * 32;
  f32x4 acc0[8], acc1[8];
  gemm_core(XB, wlds, rowb, ln, quad, nN, acc0, acc1);
  ushort* dst = half ? A2 : A1;
  epi0(acc0, rowb, ln, quad, nN, bias, half, dst);
  epi0(acc1, rowb + 16, ln, quad, nN, bias, half, dst);
}

// ---------------- standalone GEMMs ----------------
// EPI 0: gridDim.y = 2 col-halves -> A1/A2. EPI 1: H = l2norm(relu(.+deg*b)). EPI 2: f32 out.
template <int EPI>
__global__ __launch_bounds__(256) void k_gemm(const ushort* __restrict__ XB,
                                              const ushort* __restrict__ W,
                                              const float* __restrict__ bias,
                                              const int* __restrict__ deg,
                                              void* __restrict__ Y1,
                                              ushort* __restrict__ Y2, int nN) {
  __shared__ ushort wlds[128 * WPAD];
  const int t = threadIdx.x;
  const int half = (EPI == 0) ? blockIdx.y : 0;
  stage_w(W + (size_t)half * 128 * CCH, wlds, t);
  __syncthreads();
  const int wave = t >> 6, lane = t & 63;
  const int ln = lane & 15, quad = lane >> 4;
  const int rowb = blockIdx.x * 128 + wave * 32;
  f32x4 acc0[8], acc1[8];
  gemm_core(XB, wlds, rowb, ln, quad, nN, acc0, acc1);

  if constexpr (EPI == 0) {
    ushort* dst = half ? Y2 : (ushort*)Y1;
    epi0(acc0, rowb, ln, quad, nN, bias, half, dst);
    epi0(acc1, rowb + 16, ln, quad, nN, bias, half, dst);
  } else if constexpr (EPI == 1) {
    ushort* H = (ushort*)Y1;
    float biasv[8];
#pragma unroll
    for (int s = 0; s < 8; ++s) biasv[s] = bias[s * 16 + ln];
    auto epi = [&](f32x4* acc, int rb) {
#pragma unroll
      for (int r = 0; r < 4; ++r) {
        int row = rb + quad * 4 + r;
        float dn = (row < nN) ? (float)deg[row] : 0.f;
        float vals[8];
        float ss = 0.f;
#pragma unroll
        for (int s = 0; s < 8; ++s) {
          float v = fmaxf(acc[s][r] + dn * biasv[s], 0.f);
          vals[s] = v;
          ss += v * v;
        }
        ss += __shfl_xor(ss, 1, 64);
        ss += __shfl_xor(ss, 2, 64);
        ss += __shfl_xor(ss, 4, 64);
        ss += __shfl_xor(ss, 8, 64);
        float inv = 1.0f / fmaxf(sqrtf(ss), 1e-12f);
        if (row < nN) {
#pragma unroll
          for (int s = 0; s < 8; ++s)
            H[(size_t)row * CCH + s * 16 + ln] = f2b(vals[s] * inv);
        }
      }
    };
    epi(acc0, rowb); epi(acc1, rowb + 16);
  } else {
    float* OUT = (float*)Y1;
    float biasv[8];
#pragma unroll
    for (int s = 0; s < 8; ++s) biasv[s] = bias[s * 16 + ln];
    auto epi = [&](f32x4* acc, int rb) {
#pragma unroll
      for (int r = 0; r < 4; ++r) {
        int row = rb + quad * 4 + r;
        if (row >= nN) continue;
        float dn = (float)deg[row];
#pragma unroll
        for (int s = 0; s < 8; ++s)
          OUT[(size_t)row * CCH + s * 16 + ln] = acc[s][r] + dn * biasv[s];
      }
    };
    epi(acc0, rowb); epi(acc1, rowb + 16);
  }
}

// ---------------- edge aggregation v4: index shfl-broadcast + 4x unroll ----------------
__global__ __launch_bounds__(256) void k_aggr(const ushort* __restrict__ A1,
                                              const ushort* __restrict__ A2,
                                              const int* __restrict__ rowptr,
                                              const int* __restrict__ esrc,
                                              const float* __restrict__ g,
                                              const float* __restrict__ be,
                                              const float* __restrict__ rm,
                                              const float* __restrict__ rv,
                                              ushort* __restrict__ M, int nNodes) {
  int node = blockIdx.x * 4 + (threadIdx.x >> 6);
  if (node >= nNodes) return;
  int lane = threadIdx.x & 63;
  int q = lane >> 4;            // edge slot 0..3
  int c = (lane & 15) * 8;      // 8 channels per lane

  uint4 aq = *(const uint4*)&A1[(size_t)node * CCH + c];
  float a[8] = {b2f((ushort)aq.x), b2f((ushort)(aq.x >> 16)),
                b2f((ushort)aq.y), b2f((ushort)(aq.y >> 16)),
                b2f((ushort)aq.z), b2f((ushort)(aq.z >> 16)),
                b2f((ushort)aq.w), b2f((ushort)(aq.w >> 16))};
  int r0 = rowptr[node], r1 = rowptr[node + 1];
  float s[8] = {0.f, 0.f, 0.f, 0.f, 0.f, 0.f, 0.f, 0.f};

  auto acc8 = [&](uint4 w) {
    const unsigned* p = (const unsigned*)&w;
#pragma unroll
    for (int j = 0; j < 4; ++j) {
      s[2*j]   += fmaxf(a[2*j]   + b2f((ushort)p[j]), 0.f);
      s[2*j+1] += fmaxf(a[2*j+1] + b2f((ushort)(p[j] >> 16)), 0.f);
    }
  };

  for (int base = r0; base < r1; base += 64) {
    int navail = r1 - base; if (navail > 64) navail = 64;
    int myi = (lane < navail) ? esrc[base + lane] : 0;   // coalesced index prefetch
    int g4 = navail >> 2, tail = navail & 3;
    int j = 0;
    for (; j + 4 <= g4; j += 4) {       // 16 edges in flight per wave
      int p0 = j * 4 + q;
      int i0 = __shfl(myi, p0, 64);
      int i1 = __shfl(myi, p0 + 4, 64);
      int i2 = __shfl(myi, p0 + 8, 64);
      int i3 = __shfl(myi, p0 + 12, 64);
      uint4 w0 = *(const uint4*)&A2[(size_t)i0 * CCH + c];
      uint4 w1 = *(const uint4*)&A2[(size_t)i1 * CCH + c];
      uint4 w2 = *(const uint4*)&A2[(size_t)i2 * CCH + c];
      uint4 w3 = *(const uint4*)&A2[(size_t)i3 * CCH + c];
      acc8(w0); acc8(w1); acc8(w2); acc8(w3);
    }
    for (; j < g4; ++j) {
      int i0 = __shfl(myi, j * 4 + q, 64);
      acc8(*(const uint4*)&A2[(size_t)i0 * CCH + c]);
    }
    int pt = g4 * 4 + q; if (pt > 63) pt = 63;
    int it = __shfl(myi, pt, 64);       // all lanes active for shfl
    if (q < tail) acc8(*(const uint4*)&A2[(size_t)it * CCH + c]);
  }
#pragma unroll
  for (int j = 0; j < 8; ++j) {
    s[j] += __shfl_xor(s[j], 16, 64);
    s[j] += __shfl_xor(s[j], 32, 64);
  }

  if (q == 0) {
    float dn = (float)(r1 - r0);
    unsigned p[4];
#pragma unroll
    for (int j = 0; j < 4; ++j) {
      float sc0 = g[c + 2*j]     * rsqrtf(rv[c + 2*j]     + 1e-5f);
      float sc1 = g[c + 2*j + 1] * rsqrtf(rv[c + 2*j + 1] + 1e-5f);
      float o0 = sc0 * s[2*j]     + dn * (be[c + 2*j]     - rm[c + 2*j]     * sc0);
      float o1 = sc1 * s[2*j + 1] + dn * (be[c + 2*j + 1] - rm[c + 2*j + 1] * sc1);
      p[j] = (unsigned)f2b(o0) | ((unsigned)f2b(o1) << 16);
    }
    *(uint4*)&M[(size_t)node * CCH + c] = make_uint4(p[0], p[1], p[2], p[3]);
  }
}

// ---------------- launch ----------------
extern "C" void kernel_launch(void* const* d_in, const int* in_sizes, int n_in,
                              void* d_out, int out_size, void* d_ws, size_t ws_size,
                              hipStream_t stream) {
  const float* x   = (const float*)d_in[0];
  const void*  ei  = d_in[1];
  const float* w1a = (const float*)d_in[2];
  const float* b1a = (const float*)d_in[3];
  const float* g1  = (const float*)d_in[4];
  const float* be1 = (const float*)d_in[5];
  const float* rm1 = (const float*)d_in[6];
  const float* rv1 = (const float*)d_in[7];
  const float* w1b = (const float*)d_in[8];
  const float* b1b = (const float*)d_in[9];
  const float* w2a = (const float*)d_in[10];
  const float* b2a = (const float*)d_in[11];
  const float* g2  = (const float*)d_in[12];
  const float* be2 = (const float*)d_in[13];
  const float* rm2 = (const float*)d_in[14];
  const float* rv2 = (const float*)d_in[15];
  const float* w2b = (const float*)d_in[16];
  const float* b2b = (const float*)d_in[17];

  const int N = in_sizes[0] / CCH;   // 50000
  const int E = in_sizes[1] / 2;     // 600000
  const size_t NC = (size_t)N * CCH;

  int* deg    = (int*)d_ws;              // N
  int* cnt    = deg + N;                 // N
  int* rowptr = cnt + N;                 // N+1
  int* bsum   = rowptr + N + 1;          // 256
  int* esrc   = bsum + 256;              // E
  uintptr_t pw = ((uintptr_t)(esrc + E) + 63) & ~(uintptr_t)63;
  ushort* Wcat1 = (ushort*)pw;           // 256*128
  ushort* Wcat2 = Wcat1 + 32768;
  ushort* Wb1   = Wcat2 + 32768;         // 128*128
  ushort* Wb2   = Wb1 + 16384;
  uintptr_t pb = ((uintptr_t)(Wb2 + 16384) + 63) & ~(uintptr_t)63;
  ushort* XB = (ushort*)pb;              // NC bf16 (x rounded)
  ushort* B0 = XB + NC;                  // NC bf16 (A1)
  ushort* B1 = B0 + NC;                  // NC bf16 (A2)
  ushort* MB = B1 + NC;                  // NC bf16 (M)
  ushort* HB = MB + NC;                  // NC bf16 (H)

  const int gE  = (E + 255) / 256;            // 2344
  const int gS  = (N + 255) / 256;            // 196
  const int gH  = (N + 127) / 128;            // 391
  const int gA  = (N + 3) / 4;                // 12500
  const int nxc = (int)(NC / 8);              // 8-float chunks
  const int xcb = (nxc + 255) / 256;          // 3125

  hipMemsetAsync(deg, 0, sizeof(int) * 2 * (size_t)N, stream);  // deg + cnt
  k_pre<<<256 + xcb + gE, 256, 0, stream>>>(x, XB, nxc, w1a, w1b, w2a, w2b,
                                            Wcat1, Wb1, Wcat2, Wb2, ei, deg, E, xcb);
  // layer-1 EPI0 GEMM + scan1 in one grid
  k_mix1<<<2 * gH + gS, 256, 0, stream>>>(XB, Wcat1, b1a, B0, B1, N, deg, bsum, gH, N);
  k_rowptr<<<gS, 256, 0, stream>>>(deg, bsum, rowptr, N, gS, E);
  k_scatter<<<gE, 256, 0, stream>>>(ei, rowptr, cnt, esrc, E);

  k_aggr<<<gA, 256, 0, stream>>>(B0, B1, rowptr, esrc, g1, be1, rm1, rv1, MB, N);
  k_gemm<1><<<gH, 256, 0, stream>>>(MB, Wb1, b1b, deg, HB, nullptr, N);
  k_gemm<0><<<dim3(gH, 2), 256, 0, stream>>>(HB, Wcat2, b2a, deg, B0, B1, N);
  k_aggr<<<gA, 256, 0, stream>>>(B0, B1, rowptr, esrc, g2, be2, rm2, rv2, MB, N);
  k_gemm<2><<<gH, 256, 0, stream>>>(MB, Wb2, b2b, deg, d_out, nullptr, N);
}